// Round 2
// baseline (670.856 us; speedup 1.0000x reference)
//
#include <hip/hip_runtime.h>
#include <hip/hip_fp16.h>

#define N_NODES 100000
#define N_EDGES 1600000
#define N_GRAPHS 512
#define F 128
#define N_CONVS 4
#define SCAN_NBLK ((N_NODES + 1023) / 1024)   // 98
#define FILL_BLOCKS ((N_EDGES + 255) / 256)   // 6250
#define NWIN 8
#define WIN_SZ ((N_NODES + NWIN - 1) / NWIN)  // 12500 dst-nodes per window

// packed W2 row stride: 256 bf16 (hi/lo interleaved) padded to 264 = 132 dwords
#define W2_STRIDE 132
#define W2_LAYER (128 * W2_STRIDE)            // dwords per layer

typedef __attribute__((ext_vector_type(8))) short short8;   // 8 bf16 (4 VGPRs)
typedef __attribute__((ext_vector_type(4))) float f32x4;

union FragU { uint4 u; short8 v; };
union HU4 { uint4 u; __half2 h[4]; };

__device__ __forceinline__ float4 fma4(float w, float4 v, float4 a) {
    a.x = fmaf(w, v.x, a.x); a.y = fmaf(w, v.y, a.y);
    a.z = fmaf(w, v.z, a.z); a.w = fmaf(w, v.w, a.w);
    return a;
}

// split f into truncated-bf16 hi/lo, packed (hi in low16, lo in high16).
__device__ __forceinline__ unsigned int pack_hilo(float f) {
    unsigned int u = __float_as_uint(f);
    unsigned int hb = u & 0xFFFF0000u;
    float d = f - __uint_as_float(hb);
    unsigned int lb = __float_as_uint(d) >> 16;
    return (u >> 16) | (lb << 16);
}

// ---------------- CSR build ----------------

__global__ void count_kernel(const int* __restrict__ dst, int* __restrict__ cnt) {
    int e = blockIdx.x * blockDim.x + threadIdx.x;
    // nt-load the stream so the 6.4 MB dst stream doesn't evict the 400 KB
    // cnt[] atomic-target lines from L2.
    if (e < N_EDGES) atomicAdd(&cnt[__builtin_nontemporal_load(dst + e)], 1);
}

__global__ void dinv_kernel(const int* __restrict__ cnt, float* __restrict__ dinv) {
    int n = blockIdx.x * blockDim.x + threadIdx.x;
    if (n < N_NODES) dinv[n] = rsqrtf((float)cnt[n] + 2.0f);  // improved=True
}

__global__ void scan1_kernel(const int* __restrict__ cnt, int* __restrict__ excl,
                             int* __restrict__ blksum) {
    __shared__ int sums[256];
    int t = threadIdx.x;
    int base = blockIdx.x * 1024 + t * 4;
    int v0 = 0, v1 = 0, v2 = 0, v3 = 0;
    if (base + 0 < N_NODES) v0 = cnt[base + 0];
    if (base + 1 < N_NODES) v1 = cnt[base + 1];
    if (base + 2 < N_NODES) v2 = cnt[base + 2];
    if (base + 3 < N_NODES) v3 = cnt[base + 3];
    int s = v0 + v1 + v2 + v3;
    sums[t] = s;
    __syncthreads();
    for (int off = 1; off < 256; off <<= 1) {
        int y = (t >= off) ? sums[t - off] : 0;
        __syncthreads();
        sums[t] += y;
        __syncthreads();
    }
    int pre = sums[t] - s;
    if (base + 0 < N_NODES) excl[base + 0] = pre;
    if (base + 1 < N_NODES) excl[base + 1] = pre + v0;
    if (base + 2 < N_NODES) excl[base + 2] = pre + v0 + v1;
    if (base + 3 < N_NODES) excl[base + 3] = pre + v0 + v1 + v2;
    if (t == 255) blksum[blockIdx.x] = sums[255];
}

__global__ void scan2_kernel(int* __restrict__ blksum, int nblk) {
    __shared__ int sh[128];
    int t = threadIdx.x;
    int v = (t < nblk) ? blksum[t] : 0;
    sh[t] = v;
    __syncthreads();
    for (int off = 1; off < 128; off <<= 1) {
        int y = (t >= off) ? sh[t - off] : 0;
        __syncthreads();
        sh[t] += y;
        __syncthreads();
    }
    if (t < nblk) blksum[t] = sh[t] - v;
}

__global__ void scan3_kernel(int* __restrict__ rowptr, const int* __restrict__ blksum,
                             int* __restrict__ fill) {
    int t = threadIdx.x;
    int base = blockIdx.x * 1024 + t * 4;
    int off = blksum[blockIdx.x];
#pragma unroll
    for (int i = 0; i < 4; i++) {
        int idx = base + i;
        if (idx < N_NODES) {
            int v = rowptr[idx] + off;
            rowptr[idx] = v;
            fill[idx] = v;
        }
    }
    if (blockIdx.x == 0 && t == 0) rowptr[N_NODES] = N_EDGES;
}

// ---------------- XCD-pinned windowed CSR fill ----------------
// Write amplification killer, take 2. The windowing pins each dst-window's
// contiguous edges[] region (~1.6 MB) to one XCD (blockIdx%8 -> XCD), but the
// previous version still measured 101 MB WRITE_SIZE (8x ideal): each window
// pass streams the FULL 6.4 MB dst array (+src) through that XCD's 4 MB L2,
// evicting the dirty edges[] lines between their ~8 temporally-scattered
// contributions -> partial-line writeback per edge. Fix: non-temporal loads
// (evict-first) for the src/dst streams so stream lines evict EACH OTHER and
// the dirty window region stays resident until lines fully merge.
// Predicted: WRITE_SIZE 101 MB -> ~15 MB, dur 75 us -> ~35 us.

__global__ __launch_bounds__(256) void fillw_kernel(
        const int* __restrict__ src, const int* __restrict__ dst,
        const float* __restrict__ dinv, int* __restrict__ fill,
        int2* __restrict__ edges) {
    int b = blockIdx.x;
    int w = b & (NWIN - 1);
    int e = (b >> 3) * 256 + threadIdx.x;
    if (e < N_EDGES) {
        int d = __builtin_nontemporal_load(dst + e);
        if (d / WIN_SZ == w) {
            int s = __builtin_nontemporal_load(src + e);
            int pos = atomicAdd(&fill[d], 1);
            edges[pos] = make_int2(s, __float_as_int(dinv[s] * dinv[d]));
        }
    }
}

// ---------------- W pre-pack: conv_w[L][k][n] -> W2g[L][n][132 dwords] ----------------

__global__ void wpack_kernel(const float* __restrict__ conv_w, unsigned int* __restrict__ W2g) {
    int idx = blockIdx.x * 256 + threadIdx.x;
    if (idx < N_CONVS * 16384) {
        int L = idx >> 14;
        int e = idx & 16383;
        int k = e >> 7;
        int n = e & 127;
        float f = conv_w[(size_t)L * 16384 + k * 128 + n];
        W2g[(size_t)L * W2_LAYER + n * W2_STRIDE + k] = pack_hilo(f);
    }
}

// ---------------- MFMA GEMM: H = X @ W via split-bf16, 32 rows/wave, fp16 out ------

__global__ __launch_bounds__(256, 2) void gemm_mfma_kernel(const float* __restrict__ X,
                                                           const unsigned int* __restrict__ W2g,
                                                           __half* __restrict__ Hh) {
    __shared__ unsigned int wlds[128 * W2_STRIDE];   // 67584 B
    int t = threadIdx.x;

    {   // stage packed W (16896 dwords)
        const uint4* s4 = (const uint4*)W2g;
        uint4* d4 = (uint4*)wlds;
#pragma unroll
        for (int i = 0; i < 17; i++) {
            int idx = i * 256 + t;
            if (idx < (128 * W2_STRIDE) / 4) d4[idx] = s4[idx];
        }
    }
    __syncthreads();

    int w = t >> 6;
    int l = t & 63;
    int m = l & 15;        // A row within tile / B col / C col
    int q = l >> 4;        // quad: k-offset q*8, C row-offset q*4
    int r0 = blockIdx.x * 128 + w * 32 + m;
    int r1 = r0 + 16;
    int r0c = (r0 > N_NODES - 1) ? (N_NODES - 1) : r0;
    int r1c = (r1 > N_NODES - 1) ? (N_NODES - 1) : r1;
    const float4* X4 = (const float4*)X;

    uint4 a0[8], a1[8];
#pragma unroll
    for (int i = 0; i < 8; i++) {
        float4 xv = X4[(size_t)r0c * 32 + i * 4 + q];
        a0[i].x = pack_hilo(xv.x); a0[i].y = pack_hilo(xv.y);
        a0[i].z = pack_hilo(xv.z); a0[i].w = pack_hilo(xv.w);
        float4 yv = X4[(size_t)r1c * 32 + i * 4 + q];
        a1[i].x = pack_hilo(yv.x); a1[i].y = pack_hilo(yv.y);
        a1[i].z = pack_hilo(yv.z); a1[i].w = pack_hilo(yv.w);
    }

    f32x4 acc0[8], acc1[8];
#pragma unroll
    for (int nb = 0; nb < 8; nb++) {
        acc0[nb] = (f32x4){0.f, 0.f, 0.f, 0.f};
        acc1[nb] = (f32x4){0.f, 0.f, 0.f, 0.f};
    }

#pragma unroll
    for (int nb = 0; nb < 8; nb++) {
        const unsigned int* wb = &wlds[(nb * 16 + m) * W2_STRIDE];
#pragma unroll
        for (int i = 0; i < 8; i++) {
            uint4 b = *(const uint4*)(wb + i * 16 + q * 4);
            FragU fa0, fa1, fb, fr;
            fa0.u = a0[i]; fa1.u = a1[i]; fb.u = b;
            acc0[nb] = __builtin_amdgcn_mfma_f32_16x16x32_bf16(fa0.v, fb.v, acc0[nb], 0, 0, 0);
            acc1[nb] = __builtin_amdgcn_mfma_f32_16x16x32_bf16(fa1.v, fb.v, acc1[nb], 0, 0, 0);
            fr.u.x = (b.x >> 16) | (b.x << 16);
            fr.u.y = (b.y >> 16) | (b.y << 16);
            fr.u.z = (b.z >> 16) | (b.z << 16);
            fr.u.w = (b.w >> 16) | (b.w << 16);
            acc0[nb] = __builtin_amdgcn_mfma_f32_16x16x32_bf16(fa0.v, fr.v, acc0[nb], 0, 0, 0);
            acc1[nb] = __builtin_amdgcn_mfma_f32_16x16x32_bf16(fa1.v, fr.v, acc1[nb], 0, 0, 0);
        }
    }

    // C/D: col = m, row = q*4 + r within tile
    int rbase = blockIdx.x * 128 + w * 32 + q * 4;
#pragma unroll
    for (int nb = 0; nb < 8; nb++) {
#pragma unroll
        for (int r = 0; r < 4; r++) {
            int row = rbase + r;
            if (row < N_NODES) Hh[(size_t)row * F + nb * 16 + m] = __float2half(acc0[nb][r]);
            int row1 = row + 16;
            if (row1 < N_NODES) Hh[(size_t)row1 * F + nb * 16 + m] = __float2half(acc1[nb][r]);
        }
    }
}

// ---------------- Aggregation: x_out = relu(agg + 2*dinv^2*h + b), fp16 H ----------
// One wave per node; lane = (slot = lane>>4, c16 = lane&15); uint4 gathers
// (8 fp16 channels/lane, 16 lane-requests per H-row, 4 edges per instruction).
// edges[] is streamed once (12.8 MB) while H rows (25.6 MB working set) are
// gathered repeatedly -> nt-load the edges stream so it doesn't evict H in L2.

__global__ __launch_bounds__(256) void agg_kernel(const uint4* __restrict__ H16,
                                                  const int* __restrict__ rowptr,
                                                  const int2* __restrict__ edges,
                                                  const float* __restrict__ dinv,
                                                  const float4* __restrict__ bias4,
                                                  float4* __restrict__ Xo4) {
    int node = blockIdx.x * 4 + (threadIdx.x >> 6);
    if (node >= N_NODES) return;
    int lane = threadIdx.x & 63;
    int c16 = lane & 15;
    int slot = lane >> 4;

    int lo = rowptr[node];
    int hi = rowptr[node + 1];
    int him1 = hi - 1;
    const long long* edges_ll = (const long long*)edges;

    float4 aL = make_float4(0.f, 0.f, 0.f, 0.f);
    float4 aH = make_float4(0.f, 0.f, 0.f, 0.f);

    for (int i = lo + slot; i < hi; i += 16) {
        int s[4]; float w[4]; uint4 v[4];
#pragma unroll
        for (int j = 0; j < 4; j++) {
            int ij = i + 4 * j;
            int cj = (ij < him1) ? ij : him1;
            long long ev = __builtin_nontemporal_load(edges_ll + cj);
            s[j] = (int)(ev & 0xFFFFFFFFll);
            w[j] = (ij < hi) ? __int_as_float((int)(ev >> 32)) : 0.f;
        }
#pragma unroll
        for (int j = 0; j < 4; j++) v[j] = H16[(size_t)s[j] * 16 + c16];
#pragma unroll
        for (int j = 0; j < 4; j++) {
            HU4 x; x.u = v[j];
            float2 p0 = __half22float2(x.h[0]);
            float2 p1 = __half22float2(x.h[1]);
            float2 p2 = __half22float2(x.h[2]);
            float2 p3 = __half22float2(x.h[3]);
            aL.x = fmaf(w[j], p0.x, aL.x); aL.y = fmaf(w[j], p0.y, aL.y);
            aL.z = fmaf(w[j], p1.x, aL.z); aL.w = fmaf(w[j], p1.y, aL.w);
            aH.x = fmaf(w[j], p2.x, aH.x); aH.y = fmaf(w[j], p2.y, aH.y);
            aH.z = fmaf(w[j], p3.x, aH.z); aH.w = fmaf(w[j], p3.y, aH.w);
        }
    }

    aL.x += __shfl_down(aL.x, 32, 64); aL.y += __shfl_down(aL.y, 32, 64);
    aL.z += __shfl_down(aL.z, 32, 64); aL.w += __shfl_down(aL.w, 32, 64);
    aH.x += __shfl_down(aH.x, 32, 64); aH.y += __shfl_down(aH.y, 32, 64);
    aH.z += __shfl_down(aH.z, 32, 64); aH.w += __shfl_down(aH.w, 32, 64);
    aL.x += __shfl_down(aL.x, 16, 64); aL.y += __shfl_down(aL.y, 16, 64);
    aL.z += __shfl_down(aL.z, 16, 64); aL.w += __shfl_down(aL.w, 16, 64);
    aH.x += __shfl_down(aH.x, 16, 64); aH.y += __shfl_down(aH.y, 16, 64);
    aH.z += __shfl_down(aH.z, 16, 64); aH.w += __shfl_down(aH.w, 16, 64);

    if (slot == 0) {
        float dn = dinv[node];
        float sw = 2.0f * dn * dn;
        HU4 x; x.u = H16[(size_t)node * 16 + c16];
        float2 p0 = __half22float2(x.h[0]);
        float2 p1 = __half22float2(x.h[1]);
        float2 p2 = __half22float2(x.h[2]);
        float2 p3 = __half22float2(x.h[3]);
        float4 bL = bias4[c16 * 2];
        float4 bH = bias4[c16 * 2 + 1];
        float4 rL, rH;
        rL.x = fmaxf(fmaf(sw, p0.x, aL.x) + bL.x, 0.f);
        rL.y = fmaxf(fmaf(sw, p0.y, aL.y) + bL.y, 0.f);
        rL.z = fmaxf(fmaf(sw, p1.x, aL.z) + bL.z, 0.f);
        rL.w = fmaxf(fmaf(sw, p1.y, aL.w) + bL.w, 0.f);
        rH.x = fmaxf(fmaf(sw, p2.x, aH.x) + bH.x, 0.f);
        rH.y = fmaxf(fmaf(sw, p2.y, aH.y) + bH.y, 0.f);
        rH.z = fmaxf(fmaf(sw, p3.x, aH.z) + bH.z, 0.f);
        rH.w = fmaxf(fmaf(sw, p3.y, aH.w) + bH.w, 0.f);
        Xo4[(size_t)node * 32 + c16 * 2]     = rL;
        Xo4[(size_t)node * 32 + c16 * 2 + 1] = rH;
    }
}

// ---------------- Fused mean-pool + FC1(relu) + FC2 ----------------

__global__ __launch_bounds__(256) void pool_fc_kernel(const float* __restrict__ x,
                                                      const int* __restrict__ batch,
                                                      const float* __restrict__ fc1w,
                                                      const float* __restrict__ fc1b,
                                                      const float* __restrict__ fc2w,
                                                      const float* __restrict__ fc2b,
                                                      float* __restrict__ out) {
    __shared__ float part[2][F];
    __shared__ float pooled[F];
    __shared__ int bnd[2];
    __shared__ float red[2];
    int g = blockIdx.x, t = threadIdx.x;
    int c = t & 127, hlf = t >> 7;

    if (t < 2) {
        int target = g + t;
        int lo = 0, hi = N_NODES;
        while (lo < hi) {
            int m = (lo + hi) >> 1;
            if (batch[m] < target) lo = m + 1;
            else hi = m;
        }
        bnd[t] = lo;
    }
    __syncthreads();
    int lo = bnd[0], hi = bnd[1];

    float s = 0.f;
    int n = lo + hlf;
    for (; n + 6 < hi; n += 8) {
        float v0 = x[(size_t)n * F + c];
        float v1 = x[(size_t)(n + 2) * F + c];
        float v2 = x[(size_t)(n + 4) * F + c];
        float v3 = x[(size_t)(n + 6) * F + c];
        s += (v0 + v1) + (v2 + v3);
    }
    for (; n < hi; n += 2) s += x[(size_t)n * F + c];
    part[hlf][c] = s;
    __syncthreads();

    if (t < F) {
        float cntf = fmaxf((float)(hi - lo), 1.0f);
        pooled[c] = (part[0][c] + part[1][c]) / cntf;
    }
    __syncthreads();

    if (t < F) {
        float acc = fc1b[t];
#pragma unroll 4
        for (int k = 0; k < F; k++) acc = fmaf(pooled[k], fc1w[k * F + t], acc);
        acc = fmaxf(acc, 0.f);

        float p = acc * fc2w[t];
#pragma unroll
        for (int o = 32; o > 0; o >>= 1) p += __shfl_down(p, o, 64);
        if ((t & 63) == 0) red[t >> 6] = p;
    }
    __syncthreads();
    if (t == 0) out[g] = red[0] + red[1] + fc2b[0];
}

// ---------------- launch ----------------

extern "C" void kernel_launch(void* const* d_in, const int* in_sizes, int n_in,
                              void* d_out, int out_size, void* d_ws, size_t ws_size,
                              hipStream_t stream) {
    const float* x_in   = (const float*)d_in[0];
    const int*   eidx   = (const int*)d_in[1];
    const int*   batch  = (const int*)d_in[2];
    const float* conv_w = (const float*)d_in[4];
    const float* conv_b = (const float*)d_in[5];
    const float* fc1w   = (const float*)d_in[6];
    const float* fc1b   = (const float*)d_in[7];
    const float* fc2w   = (const float*)d_in[8];
    const float* fc2b   = (const float*)d_in[9];
    float* out = (float*)d_out;

    const int* src = eidx;
    const int* dst = eidx + N_EDGES;

    char* ws = (char*)d_ws;
    size_t off = 0;
    auto alloc = [&](size_t bytes) -> char* {
        char* p = ws + off;
        off += (bytes + 255) & ~(size_t)255;
        return p;
    };
    float*  bufA  = (float*)alloc((size_t)N_NODES * F * 4);    // 51.2 MB fp32 (agg out)
    __half* bufH  = (__half*)alloc((size_t)N_NODES * F * 2);   // 25.6 MB fp16 (gemm out)
    float*  dinv  = (float*)alloc((size_t)N_NODES * 4);
    int*    cnt   = (int*)alloc((size_t)N_NODES * 4);
    int*    rowp  = (int*)alloc((size_t)(N_NODES + 1) * 4);
    int*    fill  = (int*)alloc((size_t)N_NODES * 4);
    int2*   edges = (int2*)alloc((size_t)N_EDGES * 8);         // 12.8 MB packed
    unsigned int* W2g = (unsigned int*)alloc((size_t)N_CONVS * W2_LAYER * 4);  // 264 KB
    int*    blks  = (int*)alloc(128 * 4);
    (void)ws_size; (void)in_sizes; (void)n_in; (void)out_size;

    // --- CSR prep + W pre-pack ---
    hipMemsetAsync(cnt, 0, (size_t)N_NODES * 4, stream);
    count_kernel<<<(N_EDGES + 255) / 256, 256, 0, stream>>>(dst, cnt);
    dinv_kernel<<<(N_NODES + 255) / 256, 256, 0, stream>>>(cnt, dinv);
    scan1_kernel<<<SCAN_NBLK, 256, 0, stream>>>(cnt, rowp, blks);
    scan2_kernel<<<1, 128, 0, stream>>>(blks, SCAN_NBLK);
    scan3_kernel<<<SCAN_NBLK, 256, 0, stream>>>(rowp, blks, fill);
    wpack_kernel<<<(N_CONVS * 16384 + 255) / 256, 256, 0, stream>>>(conv_w, W2g);

    // --- XCD-pinned windowed CSR fill (nt streaming reads) ---
    fillw_kernel<<<FILL_BLOCKS * NWIN, 256, 0, stream>>>(src, dst, dinv, fill, edges);

    // --- 4 GCN layers: MFMA GEMM (fp16 out) + gather agg (fp32 out) ---
    const float* cur = x_in;
    for (int L = 0; L < N_CONVS; L++) {
        gemm_mfma_kernel<<<(N_NODES + 127) / 128, 256, 0, stream>>>(
            cur, W2g + (size_t)L * W2_LAYER, bufH);
        agg_kernel<<<(N_NODES + 3) / 4, 256, 0, stream>>>(
            (const uint4*)bufH, rowp, edges, dinv,
            (const float4*)(conv_b + (size_t)L * F), (float4*)bufA);
        cur = bufA;
    }

    // --- mean-pool + FC head ---
    pool_fc_kernel<<<N_GRAPHS, 256, 0, stream>>>(bufA, batch, fc1w, fc1b, fc2w, fc2b, out);
}

// Round 4
// 662.373 us; speedup vs baseline: 1.0128x; 1.0128x over previous
//
#include <hip/hip_runtime.h>
#include <hip/hip_fp16.h>

#define N_NODES 100000
#define N_EDGES 1600000
#define N_GRAPHS 512
#define F 128
#define N_CONVS 4
#define SCAN_NBLK ((N_NODES + 1023) / 1024)   // 98
#define NWIN 8
#define WIN_SZ ((N_NODES + NWIN - 1) / NWIN)  // 12500 dst-nodes per window

// two-phase fill
#define CHUNK 1024
#define BINA_BLOCKS ((N_EDGES + CHUNK - 1) / CHUNK)   // 1563
#define STG_CAP 210000                                 // mean 200k, sigma~418 -> +24 sigma
#define PB_CHUNKS ((STG_CAP + 255) / 256)              // 821 blocks per window

// packed W2 row stride: 256 bf16 (hi/lo interleaved) padded to 264 = 132 dwords
#define W2_STRIDE 132
#define W2_LAYER (128 * W2_STRIDE)            // dwords per layer

typedef __attribute__((ext_vector_type(8))) short short8;   // 8 bf16 (4 VGPRs)
typedef __attribute__((ext_vector_type(4))) float f32x4;

union FragU { uint4 u; short8 v; };
union HU4 { uint4 u; __half2 h[4]; };

// split f into truncated-bf16 hi/lo, packed (hi in low16, lo in high16).
__device__ __forceinline__ unsigned int pack_hilo(float f) {
    unsigned int u = __float_as_uint(f);
    unsigned int hb = u & 0xFFFF0000u;
    float d = f - __uint_as_float(hb);
    unsigned int lb = __float_as_uint(d) >> 16;
    return (u >> 16) | (lb << 16);
}

// ---------------- CSR build ----------------

__global__ void count_kernel(const int* __restrict__ dst, int* __restrict__ cnt) {
    int e = blockIdx.x * blockDim.x + threadIdx.x;
    if (e < N_EDGES) atomicAdd(&cnt[dst[e]], 1);
}

__global__ void dinv_kernel(const int* __restrict__ cnt, float* __restrict__ dinv) {
    int n = blockIdx.x * blockDim.x + threadIdx.x;
    if (n < N_NODES) dinv[n] = rsqrtf((float)cnt[n] + 2.0f);  // improved=True
}

__global__ void scan1_kernel(const int* __restrict__ cnt, int* __restrict__ excl,
                             int* __restrict__ blksum) {
    __shared__ int sums[256];
    int t = threadIdx.x;
    int base = blockIdx.x * 1024 + t * 4;
    int v0 = 0, v1 = 0, v2 = 0, v3 = 0;
    if (base + 0 < N_NODES) v0 = cnt[base + 0];
    if (base + 1 < N_NODES) v1 = cnt[base + 1];
    if (base + 2 < N_NODES) v2 = cnt[base + 2];
    if (base + 3 < N_NODES) v3 = cnt[base + 3];
    int s = v0 + v1 + v2 + v3;
    sums[t] = s;
    __syncthreads();
    for (int off = 1; off < 256; off <<= 1) {
        int y = (t >= off) ? sums[t - off] : 0;
        __syncthreads();
        sums[t] += y;
        __syncthreads();
    }
    int pre = sums[t] - s;
    if (base + 0 < N_NODES) excl[base + 0] = pre;
    if (base + 1 < N_NODES) excl[base + 1] = pre + v0;
    if (base + 2 < N_NODES) excl[base + 2] = pre + v0 + v1;
    if (base + 3 < N_NODES) excl[base + 3] = pre + v0 + v1 + v2;
    if (t == 255) blksum[blockIdx.x] = sums[255];
}

__global__ void scan2_kernel(int* __restrict__ blksum, int nblk) {
    __shared__ int sh[128];
    int t = threadIdx.x;
    int v = (t < nblk) ? blksum[t] : 0;
    sh[t] = v;
    __syncthreads();
    for (int off = 1; off < 128; off <<= 1) {
        int y = (t >= off) ? sh[t - off] : 0;
        __syncthreads();
        sh[t] += y;
        __syncthreads();
    }
    if (t < nblk) blksum[t] = sh[t] - v;
}

__global__ void scan3_kernel(int* __restrict__ rowptr, const int* __restrict__ blksum,
                             int* __restrict__ fill) {
    int t = threadIdx.x;
    int base = blockIdx.x * 1024 + t * 4;
    int off = blksum[blockIdx.x];
#pragma unroll
    for (int i = 0; i < 4; i++) {
        int idx = base + i;
        if (idx < N_NODES) {
            int v = rowptr[idx] + off;
            rowptr[idx] = v;
            fill[idx] = v;
        }
    }
    if (blockIdx.x == 0 && t == 0) rowptr[N_NODES] = N_EDGES;
}

// ---------------- Two-phase CSR fill ----------------
// The old 8-pass windowed fill was structure-bound: 8x re-read of dst (51 MB)
// plus temporally-scattered 8 B writes -> ~6-8x partial-line write-back
// (80-101 MB measured) at only ~1.5-2 TB/s effective. Replace with a bucket
// sort:
//  Phase A: one coalesced pass over edges; LDS-bin by dst-window; one global
//           cursor atomic per (block,window); flush bins as contiguous runs
//           into per-window staging. Full-line reads AND writes, no re-reads.
//  Phase B: blocks pinned to XCD = window (blockIdx&7) stream that window's
//           staging and scatter into the window's ~1.6 MB edges[] region.
//           stream (1.7 MB) + dirty region (1.6 MB) + fill window (50 KB)
//           fit the 4 MB XCD L2 -> scattered writes merge to full lines.

__global__ __launch_bounds__(256) void binA_kernel(
        const int* __restrict__ src, const int* __restrict__ dst,
        int* __restrict__ cursor, int2* __restrict__ staging) {
    __shared__ int2 buf[CHUNK];
    __shared__ int cnt[NWIN];
    __shared__ int off[NWIN];
    __shared__ int gbase[NWIN];
    int t = threadIdx.x;
    if (t < NWIN) cnt[t] = 0;
    __syncthreads();

    int base = blockIdx.x * CHUNK;
    int n = N_EDGES - base;
    if (n > CHUNK) n = CHUNK;

    int myw[4], myr[4], mys[4], myd[4];
#pragma unroll
    for (int j = 0; j < 4; j++) {
        int li = t + j * 256;
        if (li < n) {
            int e = base + li;
            int d = dst[e];
            int s = src[e];
            int w = d / WIN_SZ;
            myw[j] = w; mys[j] = s; myd[j] = d;
            myr[j] = atomicAdd(&cnt[w], 1);
        } else {
            myw[j] = -1;
        }
    }
    __syncthreads();

    if (t == 0) {
        int o = 0;
#pragma unroll
        for (int w = 0; w < NWIN; w++) { off[w] = o; o += cnt[w]; }
    }
    __syncthreads();

#pragma unroll
    for (int j = 0; j < 4; j++)
        if (myw[j] >= 0) buf[off[myw[j]] + myr[j]] = make_int2(mys[j], myd[j]);
    if (t < NWIN) gbase[t] = atomicAdd(&cursor[t], cnt[t]);
    __syncthreads();

    for (int w = 0; w < NWIN; w++) {
        int c = cnt[w], o = off[w], gb = gbase[w];
        for (int i = t; i < c; i += 256) {
            int idx = gb + i;
            if (idx < STG_CAP)
                staging[(size_t)w * STG_CAP + idx] = buf[o + i];
        }
    }
}

__global__ __launch_bounds__(256) void binB_kernel(
        const int2* __restrict__ staging, const int* __restrict__ cursor,
        const float* __restrict__ dinv, int* __restrict__ fill,
        int2* __restrict__ edges) {
    int b = blockIdx.x;
    int w = b & (NWIN - 1);
    int count = cursor[w];
    if (count > STG_CAP) count = STG_CAP;
    int i = (b >> 3) * 256 + threadIdx.x;
    if (i < count) {
        int2 e = staging[(size_t)w * STG_CAP + i];
        int s = e.x, d = e.y;
        float wt = dinv[s] * dinv[d];
        int pos = atomicAdd(&fill[d], 1);
        edges[pos] = make_int2(s, __float_as_int(wt));
    }
}

// ---------------- W pre-pack: conv_w[L][k][n] -> W2g[L][n][132 dwords] ----------------

__global__ void wpack_kernel(const float* __restrict__ conv_w, unsigned int* __restrict__ W2g) {
    int idx = blockIdx.x * 256 + threadIdx.x;
    if (idx < N_CONVS * 16384) {
        int L = idx >> 14;
        int e = idx & 16383;
        int k = e >> 7;
        int n = e & 127;
        float f = conv_w[(size_t)L * 16384 + k * 128 + n];
        W2g[(size_t)L * W2_LAYER + n * W2_STRIDE + k] = pack_hilo(f);
    }
}

// ---------------- MFMA GEMM: H = X @ W via split-bf16, 32 rows/wave, fp16 out ------

__global__ __launch_bounds__(256, 2) void gemm_mfma_kernel(const float* __restrict__ X,
                                                           const unsigned int* __restrict__ W2g,
                                                           __half* __restrict__ Hh) {
    __shared__ unsigned int wlds[128 * W2_STRIDE];   // 67584 B
    int t = threadIdx.x;

    {   // stage packed W (16896 dwords)
        const uint4* s4 = (const uint4*)W2g;
        uint4* d4 = (uint4*)wlds;
#pragma unroll
        for (int i = 0; i < 17; i++) {
            int idx = i * 256 + t;
            if (idx < (128 * W2_STRIDE) / 4) d4[idx] = s4[idx];
        }
    }
    __syncthreads();

    int w = t >> 6;
    int l = t & 63;
    int m = l & 15;        // A row within tile / B col / C col
    int q = l >> 4;        // quad: k-offset q*8, C row-offset q*4
    int r0 = blockIdx.x * 128 + w * 32 + m;
    int r1 = r0 + 16;
    int r0c = (r0 > N_NODES - 1) ? (N_NODES - 1) : r0;
    int r1c = (r1 > N_NODES - 1) ? (N_NODES - 1) : r1;
    const float4* X4 = (const float4*)X;

    uint4 a0[8], a1[8];
#pragma unroll
    for (int i = 0; i < 8; i++) {
        float4 xv = X4[(size_t)r0c * 32 + i * 4 + q];
        a0[i].x = pack_hilo(xv.x); a0[i].y = pack_hilo(xv.y);
        a0[i].z = pack_hilo(xv.z); a0[i].w = pack_hilo(xv.w);
        float4 yv = X4[(size_t)r1c * 32 + i * 4 + q];
        a1[i].x = pack_hilo(yv.x); a1[i].y = pack_hilo(yv.y);
        a1[i].z = pack_hilo(yv.z); a1[i].w = pack_hilo(yv.w);
    }

    f32x4 acc0[8], acc1[8];
#pragma unroll
    for (int nb = 0; nb < 8; nb++) {
        acc0[nb] = (f32x4){0.f, 0.f, 0.f, 0.f};
        acc1[nb] = (f32x4){0.f, 0.f, 0.f, 0.f};
    }

#pragma unroll
    for (int nb = 0; nb < 8; nb++) {
        const unsigned int* wb = &wlds[(nb * 16 + m) * W2_STRIDE];
#pragma unroll
        for (int i = 0; i < 8; i++) {
            uint4 b = *(const uint4*)(wb + i * 16 + q * 4);
            FragU fa0, fa1, fb, fr;
            fa0.u = a0[i]; fa1.u = a1[i]; fb.u = b;
            acc0[nb] = __builtin_amdgcn_mfma_f32_16x16x32_bf16(fa0.v, fb.v, acc0[nb], 0, 0, 0);
            acc1[nb] = __builtin_amdgcn_mfma_f32_16x16x32_bf16(fa1.v, fb.v, acc1[nb], 0, 0, 0);
            fr.u.x = (b.x >> 16) | (b.x << 16);
            fr.u.y = (b.y >> 16) | (b.y << 16);
            fr.u.z = (b.z >> 16) | (b.z << 16);
            fr.u.w = (b.w >> 16) | (b.w << 16);
            acc0[nb] = __builtin_amdgcn_mfma_f32_16x16x32_bf16(fa0.v, fr.v, acc0[nb], 0, 0, 0);
            acc1[nb] = __builtin_amdgcn_mfma_f32_16x16x32_bf16(fa1.v, fr.v, acc1[nb], 0, 0, 0);
        }
    }

    // C/D: col = m, row = q*4 + r within tile
    int rbase = blockIdx.x * 128 + w * 32 + q * 4;
#pragma unroll
    for (int nb = 0; nb < 8; nb++) {
#pragma unroll
        for (int r = 0; r < 4; r++) {
            int row = rbase + r;
            if (row < N_NODES) Hh[(size_t)row * F + nb * 16 + m] = __float2half(acc0[nb][r]);
            int row1 = row + 16;
            if (row1 < N_NODES) Hh[(size_t)row1 * F + nb * 16 + m] = __float2half(acc1[nb][r]);
        }
    }
}

// ---------------- Aggregation: x_out = relu(agg + 2*dinv^2*h + b), fp16 H ----------
// One wave per node; lane = (slot = lane>>4, c16 = lane&15); uint4 gathers
// (8 fp16 channels/lane, 16 lane-requests per H-row, 4 edges per instruction).

__global__ __launch_bounds__(256) void agg_kernel(const uint4* __restrict__ H16,
                                                  const int* __restrict__ rowptr,
                                                  const int2* __restrict__ edges,
                                                  const float* __restrict__ dinv,
                                                  const float4* __restrict__ bias4,
                                                  float4* __restrict__ Xo4) {
    int node = blockIdx.x * 4 + (threadIdx.x >> 6);
    if (node >= N_NODES) return;
    int lane = threadIdx.x & 63;
    int c16 = lane & 15;
    int slot = lane >> 4;

    int lo = rowptr[node];
    int hi = rowptr[node + 1];
    int him1 = hi - 1;

    float4 aL = make_float4(0.f, 0.f, 0.f, 0.f);
    float4 aH = make_float4(0.f, 0.f, 0.f, 0.f);

    for (int i = lo + slot; i < hi; i += 16) {
        int s[4]; float w[4]; uint4 v[4];
#pragma unroll
        for (int j = 0; j < 4; j++) {
            int ij = i + 4 * j;
            int cj = (ij < him1) ? ij : him1;
            int2 e = edges[cj];
            s[j] = e.x;
            w[j] = (ij < hi) ? __int_as_float(e.y) : 0.f;
        }
#pragma unroll
        for (int j = 0; j < 4; j++) v[j] = H16[(size_t)s[j] * 16 + c16];
#pragma unroll
        for (int j = 0; j < 4; j++) {
            HU4 x; x.u = v[j];
            float2 p0 = __half22float2(x.h[0]);
            float2 p1 = __half22float2(x.h[1]);
            float2 p2 = __half22float2(x.h[2]);
            float2 p3 = __half22float2(x.h[3]);
            aL.x = fmaf(w[j], p0.x, aL.x); aL.y = fmaf(w[j], p0.y, aL.y);
            aL.z = fmaf(w[j], p1.x, aL.z); aL.w = fmaf(w[j], p1.y, aL.w);
            aH.x = fmaf(w[j], p2.x, aH.x); aH.y = fmaf(w[j], p2.y, aH.y);
            aH.z = fmaf(w[j], p3.x, aH.z); aH.w = fmaf(w[j], p3.y, aH.w);
        }
    }

    aL.x += __shfl_down(aL.x, 32, 64); aL.y += __shfl_down(aL.y, 32, 64);
    aL.z += __shfl_down(aL.z, 32, 64); aL.w += __shfl_down(aL.w, 32, 64);
    aH.x += __shfl_down(aH.x, 32, 64); aH.y += __shfl_down(aH.y, 32, 64);
    aH.z += __shfl_down(aH.z, 32, 64); aH.w += __shfl_down(aH.w, 32, 64);
    aL.x += __shfl_down(aL.x, 16, 64); aL.y += __shfl_down(aL.y, 16, 64);
    aL.z += __shfl_down(aL.z, 16, 64); aL.w += __shfl_down(aL.w, 16, 64);
    aH.x += __shfl_down(aH.x, 16, 64); aH.y += __shfl_down(aH.y, 16, 64);
    aH.z += __shfl_down(aH.z, 16, 64); aH.w += __shfl_down(aH.w, 16, 64);

    if (slot == 0) {
        float dn = dinv[node];
        float sw = 2.0f * dn * dn;
        HU4 x; x.u = H16[(size_t)node * 16 + c16];
        float2 p0 = __half22float2(x.h[0]);
        float2 p1 = __half22float2(x.h[1]);
        float2 p2 = __half22float2(x.h[2]);
        float2 p3 = __half22float2(x.h[3]);
        float4 bL = bias4[c16 * 2];
        float4 bH = bias4[c16 * 2 + 1];
        float4 rL, rH;
        rL.x = fmaxf(fmaf(sw, p0.x, aL.x) + bL.x, 0.f);
        rL.y = fmaxf(fmaf(sw, p0.y, aL.y) + bL.y, 0.f);
        rL.z = fmaxf(fmaf(sw, p1.x, aL.z) + bL.z, 0.f);
        rL.w = fmaxf(fmaf(sw, p1.y, aL.w) + bL.w, 0.f);
        rH.x = fmaxf(fmaf(sw, p2.x, aH.x) + bH.x, 0.f);
        rH.y = fmaxf(fmaf(sw, p2.y, aH.y) + bH.y, 0.f);
        rH.z = fmaxf(fmaf(sw, p3.x, aH.z) + bH.z, 0.f);
        rH.w = fmaxf(fmaf(sw, p3.y, aH.w) + bH.w, 0.f);
        Xo4[(size_t)node * 32 + c16 * 2]     = rL;
        Xo4[(size_t)node * 32 + c16 * 2 + 1] = rH;
    }
}

// ---------------- Fused mean-pool + FC1(relu) + FC2 ----------------

__global__ __launch_bounds__(256) void pool_fc_kernel(const float* __restrict__ x,
                                                      const int* __restrict__ batch,
                                                      const float* __restrict__ fc1w,
                                                      const float* __restrict__ fc1b,
                                                      const float* __restrict__ fc2w,
                                                      const float* __restrict__ fc2b,
                                                      float* __restrict__ out) {
    __shared__ float part[2][F];
    __shared__ float pooled[F];
    __shared__ int bnd[2];
    __shared__ float red[2];
    int g = blockIdx.x, t = threadIdx.x;
    int c = t & 127, hlf = t >> 7;

    if (t < 2) {
        int target = g + t;
        int lo = 0, hi = N_NODES;
        while (lo < hi) {
            int m = (lo + hi) >> 1;
            if (batch[m] < target) lo = m + 1;
            else hi = m;
        }
        bnd[t] = lo;
    }
    __syncthreads();
    int lo = bnd[0], hi = bnd[1];

    float s = 0.f;
    int n = lo + hlf;
    for (; n + 6 < hi; n += 8) {
        float v0 = x[(size_t)n * F + c];
        float v1 = x[(size_t)(n + 2) * F + c];
        float v2 = x[(size_t)(n + 4) * F + c];
        float v3 = x[(size_t)(n + 6) * F + c];
        s += (v0 + v1) + (v2 + v3);
    }
    for (; n < hi; n += 2) s += x[(size_t)n * F + c];
    part[hlf][c] = s;
    __syncthreads();

    if (t < F) {
        float cntf = fmaxf((float)(hi - lo), 1.0f);
        pooled[c] = (part[0][c] + part[1][c]) / cntf;
    }
    __syncthreads();

    if (t < F) {
        float acc = fc1b[t];
#pragma unroll 4
        for (int k = 0; k < F; k++) acc = fmaf(pooled[k], fc1w[k * F + t], acc);
        acc = fmaxf(acc, 0.f);

        float p = acc * fc2w[t];
#pragma unroll
        for (int o = 32; o > 0; o >>= 1) p += __shfl_down(p, o, 64);
        if ((t & 63) == 0) red[t >> 6] = p;
    }
    __syncthreads();
    if (t == 0) out[g] = red[0] + red[1] + fc2b[0];
}

// ---------------- launch ----------------

extern "C" void kernel_launch(void* const* d_in, const int* in_sizes, int n_in,
                              void* d_out, int out_size, void* d_ws, size_t ws_size,
                              hipStream_t stream) {
    const float* x_in   = (const float*)d_in[0];
    const int*   eidx   = (const int*)d_in[1];
    const int*   batch  = (const int*)d_in[2];
    const float* conv_w = (const float*)d_in[4];
    const float* conv_b = (const float*)d_in[5];
    const float* fc1w   = (const float*)d_in[6];
    const float* fc1b   = (const float*)d_in[7];
    const float* fc2w   = (const float*)d_in[8];
    const float* fc2b   = (const float*)d_in[9];
    float* out = (float*)d_out;

    const int* src = eidx;
    const int* dst = eidx + N_EDGES;

    char* ws = (char*)d_ws;
    size_t off = 0;
    auto alloc = [&](size_t bytes) -> char* {
        char* p = ws + off;
        off += (bytes + 255) & ~(size_t)255;
        return p;
    };
    float*  bufA  = (float*)alloc((size_t)N_NODES * F * 4);    // 51.2 MB fp32 (agg out)
    __half* bufH  = (__half*)alloc((size_t)N_NODES * F * 2);   // 25.6 MB fp16 (gemm out)
    float*  dinv  = (float*)alloc((size_t)N_NODES * 4);
    int*    cnt   = (int*)alloc((size_t)N_NODES * 4);
    int*    rowp  = (int*)alloc((size_t)(N_NODES + 1) * 4);
    int*    fill  = (int*)alloc((size_t)N_NODES * 4);
    int2*   edges = (int2*)alloc((size_t)N_EDGES * 8);         // 12.8 MB packed
    unsigned int* W2g = (unsigned int*)alloc((size_t)N_CONVS * W2_LAYER * 4);  // 264 KB
    int*    blks  = (int*)alloc(128 * 4);
    int*    cursor = (int*)alloc(NWIN * 4);
    // staging (13.4 MB) aliases bufA: dead before the first agg_kernel writes bufA.
    int2*   staging = (int2*)bufA;
    (void)ws_size; (void)in_sizes; (void)n_in; (void)out_size;

    // --- CSR prep + W pre-pack ---
    hipMemsetAsync(cnt, 0, (size_t)N_NODES * 4, stream);
    hipMemsetAsync(cursor, 0, NWIN * 4, stream);
    count_kernel<<<(N_EDGES + 255) / 256, 256, 0, stream>>>(dst, cnt);
    dinv_kernel<<<(N_NODES + 255) / 256, 256, 0, stream>>>(cnt, dinv);
    scan1_kernel<<<SCAN_NBLK, 256, 0, stream>>>(cnt, rowp, blks);
    scan2_kernel<<<1, 128, 0, stream>>>(blks, SCAN_NBLK);
    scan3_kernel<<<SCAN_NBLK, 256, 0, stream>>>(rowp, blks, fill);
    wpack_kernel<<<(N_CONVS * 16384 + 255) / 256, 256, 0, stream>>>(conv_w, W2g);

    // --- two-phase CSR fill: bucket to per-window staging, then XCD-local scatter ---
    binA_kernel<<<BINA_BLOCKS, 256, 0, stream>>>(src, dst, cursor, staging);
    binB_kernel<<<PB_CHUNKS * NWIN, 256, 0, stream>>>(staging, cursor, dinv, fill, edges);

    // --- 4 GCN layers: MFMA GEMM (fp16 out) + gather agg (fp32 out) ---
    const float* cur = x_in;
    for (int L = 0; L < N_CONVS; L++) {
        gemm_mfma_kernel<<<(N_NODES + 127) / 128, 256, 0, stream>>>(
            cur, W2g + (size_t)L * W2_LAYER, bufH);
        agg_kernel<<<(N_NODES + 3) / 4, 256, 0, stream>>>(
            (const uint4*)bufH, rowp, edges, dinv,
            (const float4*)(conv_b + (size_t)L * F), (float4*)bufA);
        cur = bufA;
    }

    // --- mean-pool + FC head ---
    pool_fc_kernel<<<N_GRAPHS, 256, 0, stream>>>(bufA, batch, fc1w, fc1b, fc2w, fc2b, out);
}

// Round 5
// 601.895 us; speedup vs baseline: 1.1146x; 1.1005x over previous
//
#include <hip/hip_runtime.h>
#include <hip/hip_fp16.h>

#define N_NODES 100000
#define N_EDGES 1600000
#define N_GRAPHS 512
#define F 128
#define N_CONVS 4
#define SCAN_NBLK ((N_NODES + 1023) / 1024)   // 98

// two-phase fill, 256 subwindows so phase-B scatter fits in LDS
#define SUBW 256
#define SUBW_NODES 391                         // ceil(100000/256)
#define SCAP 7040                              // per-subwindow staging cap (mean 6256 + 10 sigma)
#define ACHUNK 4096
#define BINA_BLOCKS ((N_EDGES + ACHUNK - 1) / ACHUNK)  // 391
#define EBUF 8192                              // LDS edge buffer (mean 6256 + 24 sigma)

// packed W2 row stride: 256 bf16 (hi/lo interleaved) padded to 264 = 132 dwords
#define W2_STRIDE 132
#define W2_LAYER (128 * W2_STRIDE)            // dwords per layer

typedef __attribute__((ext_vector_type(8))) short short8;   // 8 bf16 (4 VGPRs)
typedef __attribute__((ext_vector_type(4))) float f32x4;

union FragU { uint4 u; short8 v; };
union HU4 { uint4 u; __half2 h[4]; };

// split f into truncated-bf16 hi/lo, packed (hi in low16, lo in high16).
__device__ __forceinline__ unsigned int pack_hilo(float f) {
    unsigned int u = __float_as_uint(f);
    unsigned int hb = u & 0xFFFF0000u;
    float d = f - __uint_as_float(hb);
    unsigned int lb = __float_as_uint(d) >> 16;
    return (u >> 16) | (lb << 16);
}

// ---------------- CSR build ----------------

__global__ void count_kernel(const int* __restrict__ dst, int* __restrict__ cnt) {
    int e = blockIdx.x * blockDim.x + threadIdx.x;
    if (e < N_EDGES) atomicAdd(&cnt[dst[e]], 1);
}

__global__ void dinv_kernel(const int* __restrict__ cnt, float* __restrict__ dinv) {
    int n = blockIdx.x * blockDim.x + threadIdx.x;
    if (n < N_NODES) dinv[n] = rsqrtf((float)cnt[n] + 2.0f);  // improved=True
}

__global__ void scan1_kernel(const int* __restrict__ cnt, int* __restrict__ excl,
                             int* __restrict__ blksum) {
    __shared__ int sums[256];
    int t = threadIdx.x;
    int base = blockIdx.x * 1024 + t * 4;
    int v0 = 0, v1 = 0, v2 = 0, v3 = 0;
    if (base + 0 < N_NODES) v0 = cnt[base + 0];
    if (base + 1 < N_NODES) v1 = cnt[base + 1];
    if (base + 2 < N_NODES) v2 = cnt[base + 2];
    if (base + 3 < N_NODES) v3 = cnt[base + 3];
    int s = v0 + v1 + v2 + v3;
    sums[t] = s;
    __syncthreads();
    for (int off = 1; off < 256; off <<= 1) {
        int y = (t >= off) ? sums[t - off] : 0;
        __syncthreads();
        sums[t] += y;
        __syncthreads();
    }
    int pre = sums[t] - s;
    if (base + 0 < N_NODES) excl[base + 0] = pre;
    if (base + 1 < N_NODES) excl[base + 1] = pre + v0;
    if (base + 2 < N_NODES) excl[base + 2] = pre + v0 + v1;
    if (base + 3 < N_NODES) excl[base + 3] = pre + v0 + v1 + v2;
    if (t == 255) blksum[blockIdx.x] = sums[255];
}

__global__ void scan2_kernel(int* __restrict__ blksum, int nblk) {
    __shared__ int sh[128];
    int t = threadIdx.x;
    int v = (t < nblk) ? blksum[t] : 0;
    sh[t] = v;
    __syncthreads();
    for (int off = 1; off < 128; off <<= 1) {
        int y = (t >= off) ? sh[t - off] : 0;
        __syncthreads();
        sh[t] += y;
        __syncthreads();
    }
    if (t < nblk) blksum[t] = sh[t] - v;
}

__global__ void scan3_kernel(int* __restrict__ rowptr, const int* __restrict__ blksum) {
    int t = threadIdx.x;
    int base = blockIdx.x * 1024 + t * 4;
    int off = blksum[blockIdx.x];
#pragma unroll
    for (int i = 0; i < 4; i++) {
        int idx = base + i;
        if (idx < N_NODES) rowptr[idx] += off;
    }
    if (blockIdx.x == 0 && t == 0) rowptr[N_NODES] = N_EDGES;
}

// ---------------- Two-phase CSR fill, LDS-ordered ----------------
// Measured lesson (fillw, fillw+nt, binB-v1): gfx950 L2 does NOT merge
// temporally-scattered 8 B stores — every scheme paid ~6x write-back
// amplification (79-101 MB for 12.8 MB of payload) no matter how small the
// dirty region was kept. So: never scatter to global. Scatter in LDS, write
// out coalesced.
//  Phase A: 256-way LDS bin per 4096-edge chunk (two-pass: count, scan,
//           scatter, flush). Staging writes are ~128 B contiguous runs.
//  Phase B: one block per 391-node subwindow (~6256 edges, fits LDS).
//           Scatter (src, weight) into exact CSR position in LDS via
//           rowptr + LDS cursors, then stream the ordered buffer to
//           edges[] fully coalesced.

__global__ __launch_bounds__(256) void binA_kernel(
        const int* __restrict__ src, const int* __restrict__ dst,
        int* __restrict__ cursor, int2* __restrict__ staging) {
    __shared__ int2 buf[ACHUNK];                 // 32 KB
    __shared__ int cnt_s[SUBW], off_s[SUBW], cur_s[SUBW], gb_s[SUBW], sh[SUBW];
    int t = threadIdx.x;
    cnt_s[t] = 0;
    __syncthreads();

    int base = blockIdx.x * ACHUNK;
    int n = N_EDGES - base;
    if (n > ACHUNK) n = ACHUNK;

    // pass 1: count bins
    for (int li = t; li < n; li += 256)
        atomicAdd(&cnt_s[dst[base + li] / SUBW_NODES], 1);
    __syncthreads();

    // exclusive scan over 256 bins
    int v = cnt_s[t];
    sh[t] = v;
    __syncthreads();
    for (int off = 1; off < SUBW; off <<= 1) {
        int y = (t >= off) ? sh[t - off] : 0;
        __syncthreads();
        sh[t] += y;
        __syncthreads();
    }
    int excl = sh[t] - v;
    off_s[t] = excl;
    cur_s[t] = excl;
    gb_s[t] = atomicAdd(&cursor[t], v);
    __syncthreads();

    // pass 2: re-read (L2-hot) and scatter into LDS bin-contiguous buffer
    for (int li = t; li < n; li += 256) {
        int e = base + li;
        int d = dst[e], s = src[e];
        int p = atomicAdd(&cur_s[d / SUBW_NODES], 1);
        buf[p] = make_int2(s, d);
    }
    __syncthreads();

    // flush: contiguous ~128 B runs per bin into per-subwindow staging
    for (int i = t; i < n; i += 256) {
        int2 e = buf[i];
        int w = e.y / SUBW_NODES;
        int idx = gb_s[w] + (i - off_s[w]);
        if (idx < SCAP) staging[(size_t)w * SCAP + idx] = e;
    }
}

__global__ __launch_bounds__(512) void binB_kernel(
        const int2* __restrict__ staging, const int* __restrict__ cursor,
        const int* __restrict__ rowptr, const float* __restrict__ dinv,
        int2* __restrict__ edges) {
    __shared__ int rowl[SUBW_NODES + 1];
    __shared__ int lcur[SUBW_NODES];
    __shared__ int2 ebuf[EBUF];                  // 64 KB
    int b = blockIdx.x, t = threadIdx.x;
    int n0 = b * SUBW_NODES;
    int n1 = n0 + SUBW_NODES;
    if (n1 > N_NODES) n1 = N_NODES;
    int nn = n1 - n0;

    for (int i = t; i <= nn; i += 512) rowl[i] = rowptr[n0 + i];
    for (int i = t; i < nn; i += 512) lcur[i] = 0;
    __syncthreads();

    int gb = rowl[0];
    int total = rowl[nn] - gb;
    int m = cursor[b];
    if (m > SCAP) m = SCAP;

    for (int i = t; i < m; i += 512) {
        int2 e = staging[(size_t)b * SCAP + i];
        int s = e.x, d = e.y;
        float wt = dinv[s] * dinv[d];
        int dl = d - n0;
        int lpos = (rowl[dl] - gb) + atomicAdd(&lcur[dl], 1);
        if (lpos < EBUF) ebuf[lpos] = make_int2(s, __float_as_int(wt));
    }
    __syncthreads();

    // fully coalesced ordered write-out of this subwindow's CSR range
    for (int i = t; i < total; i += 512)
        if (i < EBUF) edges[gb + i] = ebuf[i];
}

// ---------------- W pre-pack: conv_w[L][k][n] -> W2g[L][n][132 dwords] ----------------

__global__ void wpack_kernel(const float* __restrict__ conv_w, unsigned int* __restrict__ W2g) {
    int idx = blockIdx.x * 256 + threadIdx.x;
    if (idx < N_CONVS * 16384) {
        int L = idx >> 14;
        int e = idx & 16383;
        int k = e >> 7;
        int n = e & 127;
        float f = conv_w[(size_t)L * 16384 + k * 128 + n];
        W2g[(size_t)L * W2_LAYER + n * W2_STRIDE + k] = pack_hilo(f);
    }
}

// ---------------- MFMA GEMM: H = X @ W via split-bf16, 32 rows/wave, fp16 out ------

__global__ __launch_bounds__(256, 2) void gemm_mfma_kernel(const float* __restrict__ X,
                                                           const unsigned int* __restrict__ W2g,
                                                           __half* __restrict__ Hh) {
    __shared__ unsigned int wlds[128 * W2_STRIDE];   // 67584 B
    int t = threadIdx.x;

    {   // stage packed W (16896 dwords)
        const uint4* s4 = (const uint4*)W2g;
        uint4* d4 = (uint4*)wlds;
#pragma unroll
        for (int i = 0; i < 17; i++) {
            int idx = i * 256 + t;
            if (idx < (128 * W2_STRIDE) / 4) d4[idx] = s4[idx];
        }
    }
    __syncthreads();

    int w = t >> 6;
    int l = t & 63;
    int m = l & 15;        // A row within tile / B col / C col
    int q = l >> 4;        // quad: k-offset q*8, C row-offset q*4
    int r0 = blockIdx.x * 128 + w * 32 + m;
    int r1 = r0 + 16;
    int r0c = (r0 > N_NODES - 1) ? (N_NODES - 1) : r0;
    int r1c = (r1 > N_NODES - 1) ? (N_NODES - 1) : r1;
    const float4* X4 = (const float4*)X;

    uint4 a0[8], a1[8];
#pragma unroll
    for (int i = 0; i < 8; i++) {
        float4 xv = X4[(size_t)r0c * 32 + i * 4 + q];
        a0[i].x = pack_hilo(xv.x); a0[i].y = pack_hilo(xv.y);
        a0[i].z = pack_hilo(xv.z); a0[i].w = pack_hilo(xv.w);
        float4 yv = X4[(size_t)r1c * 32 + i * 4 + q];
        a1[i].x = pack_hilo(yv.x); a1[i].y = pack_hilo(yv.y);
        a1[i].z = pack_hilo(yv.z); a1[i].w = pack_hilo(yv.w);
    }

    f32x4 acc0[8], acc1[8];
#pragma unroll
    for (int nb = 0; nb < 8; nb++) {
        acc0[nb] = (f32x4){0.f, 0.f, 0.f, 0.f};
        acc1[nb] = (f32x4){0.f, 0.f, 0.f, 0.f};
    }

#pragma unroll
    for (int nb = 0; nb < 8; nb++) {
        const unsigned int* wb = &wlds[(nb * 16 + m) * W2_STRIDE];
#pragma unroll
        for (int i = 0; i < 8; i++) {
            uint4 b = *(const uint4*)(wb + i * 16 + q * 4);
            FragU fa0, fa1, fb, fr;
            fa0.u = a0[i]; fa1.u = a1[i]; fb.u = b;
            acc0[nb] = __builtin_amdgcn_mfma_f32_16x16x32_bf16(fa0.v, fb.v, acc0[nb], 0, 0, 0);
            acc1[nb] = __builtin_amdgcn_mfma_f32_16x16x32_bf16(fa1.v, fb.v, acc1[nb], 0, 0, 0);
            fr.u.x = (b.x >> 16) | (b.x << 16);
            fr.u.y = (b.y >> 16) | (b.y << 16);
            fr.u.z = (b.z >> 16) | (b.z << 16);
            fr.u.w = (b.w >> 16) | (b.w << 16);
            acc0[nb] = __builtin_amdgcn_mfma_f32_16x16x32_bf16(fa0.v, fr.v, acc0[nb], 0, 0, 0);
            acc1[nb] = __builtin_amdgcn_mfma_f32_16x16x32_bf16(fa1.v, fr.v, acc1[nb], 0, 0, 0);
        }
    }

    // C/D: col = m, row = q*4 + r within tile
    int rbase = blockIdx.x * 128 + w * 32 + q * 4;
#pragma unroll
    for (int nb = 0; nb < 8; nb++) {
#pragma unroll
        for (int r = 0; r < 4; r++) {
            int row = rbase + r;
            if (row < N_NODES) Hh[(size_t)row * F + nb * 16 + m] = __float2half(acc0[nb][r]);
            int row1 = row + 16;
            if (row1 < N_NODES) Hh[(size_t)row1 * F + nb * 16 + m] = __float2half(acc1[nb][r]);
        }
    }
}

// ---------------- Aggregation: x_out = relu(agg + 2*dinv^2*h + b), fp16 H ----------
// One wave per node; lane = (slot = lane>>4, c16 = lane&15); uint4 gathers
// (8 fp16 channels/lane, 16 lane-requests per H-row, 4 edges per instruction).

__global__ __launch_bounds__(256) void agg_kernel(const uint4* __restrict__ H16,
                                                  const int* __restrict__ rowptr,
                                                  const int2* __restrict__ edges,
                                                  const float* __restrict__ dinv,
                                                  const float4* __restrict__ bias4,
                                                  float4* __restrict__ Xo4) {
    int node = blockIdx.x * 4 + (threadIdx.x >> 6);
    if (node >= N_NODES) return;
    int lane = threadIdx.x & 63;
    int c16 = lane & 15;
    int slot = lane >> 4;

    int lo = rowptr[node];
    int hi = rowptr[node + 1];
    int him1 = hi - 1;

    float4 aL = make_float4(0.f, 0.f, 0.f, 0.f);
    float4 aH = make_float4(0.f, 0.f, 0.f, 0.f);

    for (int i = lo + slot; i < hi; i += 16) {
        int s[4]; float w[4]; uint4 v[4];
#pragma unroll
        for (int j = 0; j < 4; j++) {
            int ij = i + 4 * j;
            int cj = (ij < him1) ? ij : him1;
            int2 e = edges[cj];
            s[j] = e.x;
            w[j] = (ij < hi) ? __int_as_float(e.y) : 0.f;
        }
#pragma unroll
        for (int j = 0; j < 4; j++) v[j] = H16[(size_t)s[j] * 16 + c16];
#pragma unroll
        for (int j = 0; j < 4; j++) {
            HU4 x; x.u = v[j];
            float2 p0 = __half22float2(x.h[0]);
            float2 p1 = __half22float2(x.h[1]);
            float2 p2 = __half22float2(x.h[2]);
            float2 p3 = __half22float2(x.h[3]);
            aL.x = fmaf(w[j], p0.x, aL.x); aL.y = fmaf(w[j], p0.y, aL.y);
            aL.z = fmaf(w[j], p1.x, aL.z); aL.w = fmaf(w[j], p1.y, aL.w);
            aH.x = fmaf(w[j], p2.x, aH.x); aH.y = fmaf(w[j], p2.y, aH.y);
            aH.z = fmaf(w[j], p3.x, aH.z); aH.w = fmaf(w[j], p3.y, aH.w);
        }
    }

    aL.x += __shfl_down(aL.x, 32, 64); aL.y += __shfl_down(aL.y, 32, 64);
    aL.z += __shfl_down(aL.z, 32, 64); aL.w += __shfl_down(aL.w, 32, 64);
    aH.x += __shfl_down(aH.x, 32, 64); aH.y += __shfl_down(aH.y, 32, 64);
    aH.z += __shfl_down(aH.z, 32, 64); aH.w += __shfl_down(aH.w, 32, 64);
    aL.x += __shfl_down(aL.x, 16, 64); aL.y += __shfl_down(aL.y, 16, 64);
    aL.z += __shfl_down(aL.z, 16, 64); aL.w += __shfl_down(aL.w, 16, 64);
    aH.x += __shfl_down(aH.x, 16, 64); aH.y += __shfl_down(aH.y, 16, 64);
    aH.z += __shfl_down(aH.z, 16, 64); aH.w += __shfl_down(aH.w, 16, 64);

    if (slot == 0) {
        float dn = dinv[node];
        float sw = 2.0f * dn * dn;
        HU4 x; x.u = H16[(size_t)node * 16 + c16];
        float2 p0 = __half22float2(x.h[0]);
        float2 p1 = __half22float2(x.h[1]);
        float2 p2 = __half22float2(x.h[2]);
        float2 p3 = __half22float2(x.h[3]);
        float4 bL = bias4[c16 * 2];
        float4 bH = bias4[c16 * 2 + 1];
        float4 rL, rH;
        rL.x = fmaxf(fmaf(sw, p0.x, aL.x) + bL.x, 0.f);
        rL.y = fmaxf(fmaf(sw, p0.y, aL.y) + bL.y, 0.f);
        rL.z = fmaxf(fmaf(sw, p1.x, aL.z) + bL.z, 0.f);
        rL.w = fmaxf(fmaf(sw, p1.y, aL.w) + bL.w, 0.f);
        rH.x = fmaxf(fmaf(sw, p2.x, aH.x) + bH.x, 0.f);
        rH.y = fmaxf(fmaf(sw, p2.y, aH.y) + bH.y, 0.f);
        rH.z = fmaxf(fmaf(sw, p3.x, aH.z) + bH.z, 0.f);
        rH.w = fmaxf(fmaf(sw, p3.y, aH.w) + bH.w, 0.f);
        Xo4[(size_t)node * 32 + c16 * 2]     = rL;
        Xo4[(size_t)node * 32 + c16 * 2 + 1] = rH;
    }
}

// ---------------- Fused mean-pool + FC1(relu) + FC2 ----------------

__global__ __launch_bounds__(256) void pool_fc_kernel(const float* __restrict__ x,
                                                      const int* __restrict__ batch,
                                                      const float* __restrict__ fc1w,
                                                      const float* __restrict__ fc1b,
                                                      const float* __restrict__ fc2w,
                                                      const float* __restrict__ fc2b,
                                                      float* __restrict__ out) {
    __shared__ float part[2][F];
    __shared__ float pooled[F];
    __shared__ int bnd[2];
    __shared__ float red[2];
    int g = blockIdx.x, t = threadIdx.x;
    int c = t & 127, hlf = t >> 7;

    if (t < 2) {
        int target = g + t;
        int lo = 0, hi = N_NODES;
        while (lo < hi) {
            int m = (lo + hi) >> 1;
            if (batch[m] < target) lo = m + 1;
            else hi = m;
        }
        bnd[t] = lo;
    }
    __syncthreads();
    int lo = bnd[0], hi = bnd[1];

    float s = 0.f;
    int n = lo + hlf;
    for (; n + 6 < hi; n += 8) {
        float v0 = x[(size_t)n * F + c];
        float v1 = x[(size_t)(n + 2) * F + c];
        float v2 = x[(size_t)(n + 4) * F + c];
        float v3 = x[(size_t)(n + 6) * F + c];
        s += (v0 + v1) + (v2 + v3);
    }
    for (; n < hi; n += 2) s += x[(size_t)n * F + c];
    part[hlf][c] = s;
    __syncthreads();

    if (t < F) {
        float cntf = fmaxf((float)(hi - lo), 1.0f);
        pooled[c] = (part[0][c] + part[1][c]) / cntf;
    }
    __syncthreads();

    if (t < F) {
        float acc = fc1b[t];
#pragma unroll 4
        for (int k = 0; k < F; k++) acc = fmaf(pooled[k], fc1w[k * F + t], acc);
        acc = fmaxf(acc, 0.f);

        float p = acc * fc2w[t];
#pragma unroll
        for (int o = 32; o > 0; o >>= 1) p += __shfl_down(p, o, 64);
        if ((t & 63) == 0) red[t >> 6] = p;
    }
    __syncthreads();
    if (t == 0) out[g] = red[0] + red[1] + fc2b[0];
}

// ---------------- launch ----------------

extern "C" void kernel_launch(void* const* d_in, const int* in_sizes, int n_in,
                              void* d_out, int out_size, void* d_ws, size_t ws_size,
                              hipStream_t stream) {
    const float* x_in   = (const float*)d_in[0];
    const int*   eidx   = (const int*)d_in[1];
    const int*   batch  = (const int*)d_in[2];
    const float* conv_w = (const float*)d_in[4];
    const float* conv_b = (const float*)d_in[5];
    const float* fc1w   = (const float*)d_in[6];
    const float* fc1b   = (const float*)d_in[7];
    const float* fc2w   = (const float*)d_in[8];
    const float* fc2b   = (const float*)d_in[9];
    float* out = (float*)d_out;

    const int* src = eidx;
    const int* dst = eidx + N_EDGES;

    char* ws = (char*)d_ws;
    size_t off = 0;
    auto alloc = [&](size_t bytes) -> char* {
        char* p = ws + off;
        off += (bytes + 255) & ~(size_t)255;
        return p;
    };
    float*  bufA  = (float*)alloc((size_t)N_NODES * F * 4);    // 51.2 MB fp32 (agg out)
    __half* bufH  = (__half*)alloc((size_t)N_NODES * F * 2);   // 25.6 MB fp16 (gemm out)
    float*  dinv  = (float*)alloc((size_t)N_NODES * 4);
    int*    cnt   = (int*)alloc((size_t)N_NODES * 4);
    int*    rowp  = (int*)alloc((size_t)(N_NODES + 1) * 4);
    int2*   edges = (int2*)alloc((size_t)N_EDGES * 8);         // 12.8 MB packed
    unsigned int* W2g = (unsigned int*)alloc((size_t)N_CONVS * W2_LAYER * 4);  // 264 KB
    int*    blks  = (int*)alloc(128 * 4);
    int*    cursor = (int*)alloc(SUBW * 4);
    // staging (14.4 MB) aliases bufA: dead before the first agg_kernel writes bufA.
    int2*   staging = (int2*)bufA;
    (void)ws_size; (void)in_sizes; (void)n_in; (void)out_size;

    // --- CSR prep + W pre-pack ---
    hipMemsetAsync(cnt, 0, (size_t)N_NODES * 4, stream);
    hipMemsetAsync(cursor, 0, SUBW * 4, stream);
    count_kernel<<<(N_EDGES + 255) / 256, 256, 0, stream>>>(dst, cnt);
    dinv_kernel<<<(N_NODES + 255) / 256, 256, 0, stream>>>(cnt, dinv);
    scan1_kernel<<<SCAN_NBLK, 256, 0, stream>>>(cnt, rowp, blks);
    scan2_kernel<<<1, 128, 0, stream>>>(blks, SCAN_NBLK);
    scan3_kernel<<<SCAN_NBLK, 256, 0, stream>>>(rowp, blks);
    wpack_kernel<<<(N_CONVS * 16384 + 255) / 256, 256, 0, stream>>>(conv_w, W2g);

    // --- two-phase CSR fill: 256-way bucket, then LDS-ordered coalesced write ---
    binA_kernel<<<BINA_BLOCKS, 256, 0, stream>>>(src, dst, cursor, staging);
    binB_kernel<<<SUBW, 512, 0, stream>>>(staging, cursor, rowp, dinv, edges);

    // --- 4 GCN layers: MFMA GEMM (fp16 out) + gather agg (fp32 out) ---
    const float* cur = x_in;
    for (int L = 0; L < N_CONVS; L++) {
        gemm_mfma_kernel<<<(N_NODES + 127) / 128, 256, 0, stream>>>(
            cur, W2g + (size_t)L * W2_LAYER, bufH);
        agg_kernel<<<(N_NODES + 3) / 4, 256, 0, stream>>>(
            (const uint4*)bufH, rowp, edges, dinv,
            (const float4*)(conv_b + (size_t)L * F), (float4*)bufA);
        cur = bufA;
    }

    // --- mean-pool + FC head ---
    pool_fc_kernel<<<N_GRAPHS, 256, 0, stream>>>(bufA, batch, fc1w, fc1b, fc2w, fc2b, out);
}

// Round 6
// 544.443 us; speedup vs baseline: 1.2322x; 1.1055x over previous
//
#include <hip/hip_runtime.h>
#include <hip/hip_fp16.h>

#define N_NODES 100000
#define N_EDGES 1600000
#define N_GRAPHS 512
#define F 128
#define N_CONVS 4
#define SCAN_NBLK ((N_NODES + 1023) / 1024)   // 98

// two-phase fill, 256 subwindows so phase-B scatter fits in LDS
#define SUBW 256
#define SUBW_NODES 391                         // ceil(100000/256)
#define SCAP 7040                              // per-subwindow staging cap (mean 6256 + 10 sigma)
#define ACHUNK 4096
#define BINA_BLOCKS ((N_EDGES + ACHUNK - 1) / ACHUNK)  // 391
#define EBUF 8192                              // LDS edge buffer (mean 6256 + 24 sigma)

// packed W2 row stride: 256 bf16 (hi/lo interleaved) padded to 264 = 132 dwords
#define W2_STRIDE 132
#define W2_LAYER (128 * W2_STRIDE)            // dwords per layer

typedef __attribute__((ext_vector_type(8))) short short8;   // 8 bf16 (4 VGPRs)
typedef __attribute__((ext_vector_type(4))) float f32x4;

union FragU { uint4 u; short8 v; };
union HU4 { uint4 u; __half2 h[4]; };

// split f into truncated-bf16 hi/lo, packed (hi in low16, lo in high16).
__device__ __forceinline__ unsigned int pack_hilo(float f) {
    unsigned int u = __float_as_uint(f);
    unsigned int hb = u & 0xFFFF0000u;
    float d = f - __uint_as_float(hb);
    unsigned int lb = __float_as_uint(d) >> 16;
    return (u >> 16) | (lb << 16);
}

// ---------------- CSR build ----------------

__global__ void dinv_kernel(const int* __restrict__ cnt, float* __restrict__ dinv) {
    int n = blockIdx.x * blockDim.x + threadIdx.x;
    if (n < N_NODES) dinv[n] = rsqrtf((float)cnt[n] + 2.0f);  // improved=True
}

__global__ void scan1_kernel(const int* __restrict__ cnt, int* __restrict__ excl,
                             int* __restrict__ blksum) {
    __shared__ int sums[256];
    int t = threadIdx.x;
    int base = blockIdx.x * 1024 + t * 4;
    int v0 = 0, v1 = 0, v2 = 0, v3 = 0;
    if (base + 0 < N_NODES) v0 = cnt[base + 0];
    if (base + 1 < N_NODES) v1 = cnt[base + 1];
    if (base + 2 < N_NODES) v2 = cnt[base + 2];
    if (base + 3 < N_NODES) v3 = cnt[base + 3];
    int s = v0 + v1 + v2 + v3;
    sums[t] = s;
    __syncthreads();
    for (int off = 1; off < 256; off <<= 1) {
        int y = (t >= off) ? sums[t - off] : 0;
        __syncthreads();
        sums[t] += y;
        __syncthreads();
    }
    int pre = sums[t] - s;
    if (base + 0 < N_NODES) excl[base + 0] = pre;
    if (base + 1 < N_NODES) excl[base + 1] = pre + v0;
    if (base + 2 < N_NODES) excl[base + 2] = pre + v0 + v1;
    if (base + 3 < N_NODES) excl[base + 3] = pre + v0 + v1 + v2;
    if (t == 255) blksum[blockIdx.x] = sums[255];
}

__global__ void scan2_kernel(int* __restrict__ blksum, int nblk) {
    __shared__ int sh[128];
    int t = threadIdx.x;
    int v = (t < nblk) ? blksum[t] : 0;
    sh[t] = v;
    __syncthreads();
    for (int off = 1; off < 128; off <<= 1) {
        int y = (t >= off) ? sh[t - off] : 0;
        __syncthreads();
        sh[t] += y;
        __syncthreads();
    }
    if (t < nblk) blksum[t] = sh[t] - v;
}

__global__ void scan3_kernel(int* __restrict__ rowptr, const int* __restrict__ blksum) {
    int t = threadIdx.x;
    int base = blockIdx.x * 1024 + t * 4;
    int off = blksum[blockIdx.x];
#pragma unroll
    for (int i = 0; i < 4; i++) {
        int idx = base + i;
        if (idx < N_NODES) rowptr[idx] += off;
    }
    if (blockIdx.x == 0 && t == 0) rowptr[N_NODES] = N_EDGES;
}

// ---------------- Two-phase CSR fill, LDS-ordered ----------------
// Measured lessons:
//  (1) gfx950 L2 does NOT merge temporally-scattered 8 B stores — every
//      global-scatter scheme paid ~6x write-back amplification. Scatter in
//      LDS, write out coalesced.
//  (2) gfx950 global atomics scattered over a small array are also ~64 B
//      write-back each (count_kernel: 50 MB WRITE for 400 KB of counters,
//      70 us). Per-XCD L2s are non-coherent, so device atomics RMW at the
//      memory-side point. Count in LDS per subwindow instead (subcount).
//  Phase A: 256-way LDS bin per 4096-edge chunk (needs no counts).
//  subcount: one block per subwindow, LDS histogram of its staged edges,
//            coalesced cnt[] write. Replaces the atomic count_kernel.
//  Phase B: one block per subwindow (~6256 edges, fits LDS). Scatter
//           (src, weight) into exact CSR position in LDS via rowptr + LDS
//           cursors, then stream the ordered buffer to edges[] coalesced.

__global__ __launch_bounds__(256) void binA_kernel(
        const int* __restrict__ src, const int* __restrict__ dst,
        int* __restrict__ cursor, int2* __restrict__ staging) {
    __shared__ int2 buf[ACHUNK];                 // 32 KB
    __shared__ int cnt_s[SUBW], off_s[SUBW], cur_s[SUBW], gb_s[SUBW], sh[SUBW];
    int t = threadIdx.x;
    cnt_s[t] = 0;
    __syncthreads();

    int base = blockIdx.x * ACHUNK;
    int n = N_EDGES - base;
    if (n > ACHUNK) n = ACHUNK;

    // pass 1: count bins
    for (int li = t; li < n; li += 256)
        atomicAdd(&cnt_s[dst[base + li] / SUBW_NODES], 1);
    __syncthreads();

    // exclusive scan over 256 bins
    int v = cnt_s[t];
    sh[t] = v;
    __syncthreads();
    for (int off = 1; off < SUBW; off <<= 1) {
        int y = (t >= off) ? sh[t - off] : 0;
        __syncthreads();
        sh[t] += y;
        __syncthreads();
    }
    int excl = sh[t] - v;
    off_s[t] = excl;
    cur_s[t] = excl;
    gb_s[t] = atomicAdd(&cursor[t], v);
    __syncthreads();

    // pass 2: re-read (L2-hot) and scatter into LDS bin-contiguous buffer
    for (int li = t; li < n; li += 256) {
        int e = base + li;
        int d = dst[e], s = src[e];
        int p = atomicAdd(&cur_s[d / SUBW_NODES], 1);
        buf[p] = make_int2(s, d);
    }
    __syncthreads();

    // flush: contiguous ~128 B runs per bin into per-subwindow staging
    for (int i = t; i < n; i += 256) {
        int2 e = buf[i];
        int w = e.y / SUBW_NODES;
        int idx = gb_s[w] + (i - off_s[w]);
        if (idx < SCAP) staging[(size_t)w * SCAP + idx] = e;
    }
}

__global__ __launch_bounds__(256) void subcount_kernel(
        const int2* __restrict__ staging, const int* __restrict__ cursor,
        int* __restrict__ cnt) {
    __shared__ int hist[SUBW_NODES];
    int b = blockIdx.x, t = threadIdx.x;
    int n0 = b * SUBW_NODES;
    int n1 = n0 + SUBW_NODES;
    if (n1 > N_NODES) n1 = N_NODES;
    int nn = n1 - n0;
    for (int i = t; i < nn; i += 256) hist[i] = 0;
    __syncthreads();
    int m = cursor[b];
    if (m > SCAP) m = SCAP;
    for (int i = t; i < m; i += 256) {
        int d = staging[(size_t)b * SCAP + i].y;
        atomicAdd(&hist[d - n0], 1);
    }
    __syncthreads();
    for (int i = t; i < nn; i += 256) cnt[n0 + i] = hist[i];
}

__global__ __launch_bounds__(512) void binB_kernel(
        const int2* __restrict__ staging, const int* __restrict__ cursor,
        const int* __restrict__ rowptr, const float* __restrict__ dinv,
        int2* __restrict__ edges) {
    __shared__ int rowl[SUBW_NODES + 1];
    __shared__ int lcur[SUBW_NODES];
    __shared__ int2 ebuf[EBUF];                  // 64 KB
    int b = blockIdx.x, t = threadIdx.x;
    int n0 = b * SUBW_NODES;
    int n1 = n0 + SUBW_NODES;
    if (n1 > N_NODES) n1 = N_NODES;
    int nn = n1 - n0;

    for (int i = t; i <= nn; i += 512) rowl[i] = rowptr[n0 + i];
    for (int i = t; i < nn; i += 512) lcur[i] = 0;
    __syncthreads();

    int gb = rowl[0];
    int total = rowl[nn] - gb;
    int m = cursor[b];
    if (m > SCAP) m = SCAP;

    for (int i = t; i < m; i += 512) {
        int2 e = staging[(size_t)b * SCAP + i];
        int s = e.x, d = e.y;
        float wt = dinv[s] * dinv[d];
        int dl = d - n0;
        int lpos = (rowl[dl] - gb) + atomicAdd(&lcur[dl], 1);
        if (lpos < EBUF) ebuf[lpos] = make_int2(s, __float_as_int(wt));
    }
    __syncthreads();

    // fully coalesced ordered write-out of this subwindow's CSR range
    for (int i = t; i < total; i += 512)
        if (i < EBUF) edges[gb + i] = ebuf[i];
}

// ---------------- W pre-pack: conv_w[L][k][n] -> W2g[L][n][132 dwords] ----------------

__global__ void wpack_kernel(const float* __restrict__ conv_w, unsigned int* __restrict__ W2g) {
    int idx = blockIdx.x * 256 + threadIdx.x;
    if (idx < N_CONVS * 16384) {
        int L = idx >> 14;
        int e = idx & 16383;
        int k = e >> 7;
        int n = e & 127;
        float f = conv_w[(size_t)L * 16384 + k * 128 + n];
        W2g[(size_t)L * W2_LAYER + n * W2_STRIDE + k] = pack_hilo(f);
    }
}

// ---------------- MFMA GEMM: H = X @ W via split-bf16, 32 rows/wave, fp16 out ------

__global__ __launch_bounds__(256, 2) void gemm_mfma_kernel(const float* __restrict__ X,
                                                           const unsigned int* __restrict__ W2g,
                                                           __half* __restrict__ Hh) {
    __shared__ unsigned int wlds[128 * W2_STRIDE];   // 67584 B
    int t = threadIdx.x;

    {   // stage packed W (16896 dwords)
        const uint4* s4 = (const uint4*)W2g;
        uint4* d4 = (uint4*)wlds;
#pragma unroll
        for (int i = 0; i < 17; i++) {
            int idx = i * 256 + t;
            if (idx < (128 * W2_STRIDE) / 4) d4[idx] = s4[idx];
        }
    }
    __syncthreads();

    int w = t >> 6;
    int l = t & 63;
    int m = l & 15;        // A row within tile / B col / C col
    int q = l >> 4;        // quad: k-offset q*8, C row-offset q*4
    int r0 = blockIdx.x * 128 + w * 32 + m;
    int r1 = r0 + 16;
    int r0c = (r0 > N_NODES - 1) ? (N_NODES - 1) : r0;
    int r1c = (r1 > N_NODES - 1) ? (N_NODES - 1) : r1;
    const float4* X4 = (const float4*)X;

    uint4 a0[8], a1[8];
#pragma unroll
    for (int i = 0; i < 8; i++) {
        float4 xv = X4[(size_t)r0c * 32 + i * 4 + q];
        a0[i].x = pack_hilo(xv.x); a0[i].y = pack_hilo(xv.y);
        a0[i].z = pack_hilo(xv.z); a0[i].w = pack_hilo(xv.w);
        float4 yv = X4[(size_t)r1c * 32 + i * 4 + q];
        a1[i].x = pack_hilo(yv.x); a1[i].y = pack_hilo(yv.y);
        a1[i].z = pack_hilo(yv.z); a1[i].w = pack_hilo(yv.w);
    }

    f32x4 acc0[8], acc1[8];
#pragma unroll
    for (int nb = 0; nb < 8; nb++) {
        acc0[nb] = (f32x4){0.f, 0.f, 0.f, 0.f};
        acc1[nb] = (f32x4){0.f, 0.f, 0.f, 0.f};
    }

#pragma unroll
    for (int nb = 0; nb < 8; nb++) {
        const unsigned int* wb = &wlds[(nb * 16 + m) * W2_STRIDE];
#pragma unroll
        for (int i = 0; i < 8; i++) {
            uint4 b = *(const uint4*)(wb + i * 16 + q * 4);
            FragU fa0, fa1, fb, fr;
            fa0.u = a0[i]; fa1.u = a1[i]; fb.u = b;
            acc0[nb] = __builtin_amdgcn_mfma_f32_16x16x32_bf16(fa0.v, fb.v, acc0[nb], 0, 0, 0);
            acc1[nb] = __builtin_amdgcn_mfma_f32_16x16x32_bf16(fa1.v, fb.v, acc1[nb], 0, 0, 0);
            fr.u.x = (b.x >> 16) | (b.x << 16);
            fr.u.y = (b.y >> 16) | (b.y << 16);
            fr.u.z = (b.z >> 16) | (b.z << 16);
            fr.u.w = (b.w >> 16) | (b.w << 16);
            acc0[nb] = __builtin_amdgcn_mfma_f32_16x16x32_bf16(fa0.v, fr.v, acc0[nb], 0, 0, 0);
            acc1[nb] = __builtin_amdgcn_mfma_f32_16x16x32_bf16(fa1.v, fr.v, acc1[nb], 0, 0, 0);
        }
    }

    // C/D: col = m, row = q*4 + r within tile
    int rbase = blockIdx.x * 128 + w * 32 + q * 4;
#pragma unroll
    for (int nb = 0; nb < 8; nb++) {
#pragma unroll
        for (int r = 0; r < 4; r++) {
            int row = rbase + r;
            if (row < N_NODES) Hh[(size_t)row * F + nb * 16 + m] = __float2half(acc0[nb][r]);
            int row1 = row + 16;
            if (row1 < N_NODES) Hh[(size_t)row1 * F + nb * 16 + m] = __float2half(acc1[nb][r]);
        }
    }
}

// ---------------- Aggregation: x_out = relu(agg + 2*dinv^2*h + b), fp16 H ----------
// One wave per node; lane = (slot = lane>>4, c16 = lane&15); uint4 gathers
// (8 fp16 channels/lane, 16 lane-requests per H-row, 4 edges per instruction).

__global__ __launch_bounds__(256) void agg_kernel(const uint4* __restrict__ H16,
                                                  const int* __restrict__ rowptr,
                                                  const int2* __restrict__ edges,
                                                  const float* __restrict__ dinv,
                                                  const float4* __restrict__ bias4,
                                                  float4* __restrict__ Xo4) {
    int node = blockIdx.x * 4 + (threadIdx.x >> 6);
    if (node >= N_NODES) return;
    int lane = threadIdx.x & 63;
    int c16 = lane & 15;
    int slot = lane >> 4;

    int lo = rowptr[node];
    int hi = rowptr[node + 1];
    int him1 = hi - 1;

    float4 aL = make_float4(0.f, 0.f, 0.f, 0.f);
    float4 aH = make_float4(0.f, 0.f, 0.f, 0.f);

    for (int i = lo + slot; i < hi; i += 16) {
        int s[4]; float w[4]; uint4 v[4];
#pragma unroll
        for (int j = 0; j < 4; j++) {
            int ij = i + 4 * j;
            int cj = (ij < him1) ? ij : him1;
            int2 e = edges[cj];
            s[j] = e.x;
            w[j] = (ij < hi) ? __int_as_float(e.y) : 0.f;
        }
#pragma unroll
        for (int j = 0; j < 4; j++) v[j] = H16[(size_t)s[j] * 16 + c16];
#pragma unroll
        for (int j = 0; j < 4; j++) {
            HU4 x; x.u = v[j];
            float2 p0 = __half22float2(x.h[0]);
            float2 p1 = __half22float2(x.h[1]);
            float2 p2 = __half22float2(x.h[2]);
            float2 p3 = __half22float2(x.h[3]);
            aL.x = fmaf(w[j], p0.x, aL.x); aL.y = fmaf(w[j], p0.y, aL.y);
            aL.z = fmaf(w[j], p1.x, aL.z); aL.w = fmaf(w[j], p1.y, aL.w);
            aH.x = fmaf(w[j], p2.x, aH.x); aH.y = fmaf(w[j], p2.y, aH.y);
            aH.z = fmaf(w[j], p3.x, aH.z); aH.w = fmaf(w[j], p3.y, aH.w);
        }
    }

    aL.x += __shfl_down(aL.x, 32, 64); aL.y += __shfl_down(aL.y, 32, 64);
    aL.z += __shfl_down(aL.z, 32, 64); aL.w += __shfl_down(aL.w, 32, 64);
    aH.x += __shfl_down(aH.x, 32, 64); aH.y += __shfl_down(aH.y, 32, 64);
    aH.z += __shfl_down(aH.z, 32, 64); aH.w += __shfl_down(aH.w, 32, 64);
    aL.x += __shfl_down(aL.x, 16, 64); aL.y += __shfl_down(aL.y, 16, 64);
    aL.z += __shfl_down(aL.z, 16, 64); aL.w += __shfl_down(aL.w, 16, 64);
    aH.x += __shfl_down(aH.x, 16, 64); aH.y += __shfl_down(aH.y, 16, 64);
    aH.z += __shfl_down(aH.z, 16, 64); aH.w += __shfl_down(aH.w, 16, 64);

    if (slot == 0) {
        float dn = dinv[node];
        float sw = 2.0f * dn * dn;
        HU4 x; x.u = H16[(size_t)node * 16 + c16];
        float2 p0 = __half22float2(x.h[0]);
        float2 p1 = __half22float2(x.h[1]);
        float2 p2 = __half22float2(x.h[2]);
        float2 p3 = __half22float2(x.h[3]);
        float4 bL = bias4[c16 * 2];
        float4 bH = bias4[c16 * 2 + 1];
        float4 rL, rH;
        rL.x = fmaxf(fmaf(sw, p0.x, aL.x) + bL.x, 0.f);
        rL.y = fmaxf(fmaf(sw, p0.y, aL.y) + bL.y, 0.f);
        rL.z = fmaxf(fmaf(sw, p1.x, aL.z) + bL.z, 0.f);
        rL.w = fmaxf(fmaf(sw, p1.y, aL.w) + bL.w, 0.f);
        rH.x = fmaxf(fmaf(sw, p2.x, aH.x) + bH.x, 0.f);
        rH.y = fmaxf(fmaf(sw, p2.y, aH.y) + bH.y, 0.f);
        rH.z = fmaxf(fmaf(sw, p3.x, aH.z) + bH.z, 0.f);
        rH.w = fmaxf(fmaf(sw, p3.y, aH.w) + bH.w, 0.f);
        Xo4[(size_t)node * 32 + c16 * 2]     = rL;
        Xo4[(size_t)node * 32 + c16 * 2 + 1] = rH;
    }
}

// ---------------- Fused mean-pool + FC1(relu) + FC2 ----------------

__global__ __launch_bounds__(256) void pool_fc_kernel(const float* __restrict__ x,
                                                      const int* __restrict__ batch,
                                                      const float* __restrict__ fc1w,
                                                      const float* __restrict__ fc1b,
                                                      const float* __restrict__ fc2w,
                                                      const float* __restrict__ fc2b,
                                                      float* __restrict__ out) {
    __shared__ float part[2][F];
    __shared__ float pooled[F];
    __shared__ int bnd[2];
    __shared__ float red[2];
    int g = blockIdx.x, t = threadIdx.x;
    int c = t & 127, hlf = t >> 7;

    if (t < 2) {
        int target = g + t;
        int lo = 0, hi = N_NODES;
        while (lo < hi) {
            int m = (lo + hi) >> 1;
            if (batch[m] < target) lo = m + 1;
            else hi = m;
        }
        bnd[t] = lo;
    }
    __syncthreads();
    int lo = bnd[0], hi = bnd[1];

    float s = 0.f;
    int n = lo + hlf;
    for (; n + 6 < hi; n += 8) {
        float v0 = x[(size_t)n * F + c];
        float v1 = x[(size_t)(n + 2) * F + c];
        float v2 = x[(size_t)(n + 4) * F + c];
        float v3 = x[(size_t)(n + 6) * F + c];
        s += (v0 + v1) + (v2 + v3);
    }
    for (; n < hi; n += 2) s += x[(size_t)n * F + c];
    part[hlf][c] = s;
    __syncthreads();

    if (t < F) {
        float cntf = fmaxf((float)(hi - lo), 1.0f);
        pooled[c] = (part[0][c] + part[1][c]) / cntf;
    }
    __syncthreads();

    if (t < F) {
        float acc = fc1b[t];
#pragma unroll 4
        for (int k = 0; k < F; k++) acc = fmaf(pooled[k], fc1w[k * F + t], acc);
        acc = fmaxf(acc, 0.f);

        float p = acc * fc2w[t];
#pragma unroll
        for (int o = 32; o > 0; o >>= 1) p += __shfl_down(p, o, 64);
        if ((t & 63) == 0) red[t >> 6] = p;
    }
    __syncthreads();
    if (t == 0) out[g] = red[0] + red[1] + fc2b[0];
}

// ---------------- launch ----------------

extern "C" void kernel_launch(void* const* d_in, const int* in_sizes, int n_in,
                              void* d_out, int out_size, void* d_ws, size_t ws_size,
                              hipStream_t stream) {
    const float* x_in   = (const float*)d_in[0];
    const int*   eidx   = (const int*)d_in[1];
    const int*   batch  = (const int*)d_in[2];
    const float* conv_w = (const float*)d_in[4];
    const float* conv_b = (const float*)d_in[5];
    const float* fc1w   = (const float*)d_in[6];
    const float* fc1b   = (const float*)d_in[7];
    const float* fc2w   = (const float*)d_in[8];
    const float* fc2b   = (const float*)d_in[9];
    float* out = (float*)d_out;

    const int* src = eidx;
    const int* dst = eidx + N_EDGES;

    char* ws = (char*)d_ws;
    size_t off = 0;
    auto alloc = [&](size_t bytes) -> char* {
        char* p = ws + off;
        off += (bytes + 255) & ~(size_t)255;
        return p;
    };
    float*  bufA  = (float*)alloc((size_t)N_NODES * F * 4);    // 51.2 MB fp32 (agg out)
    __half* bufH  = (__half*)alloc((size_t)N_NODES * F * 2);   // 25.6 MB fp16 (gemm out)
    float*  dinv  = (float*)alloc((size_t)N_NODES * 4);
    int*    cnt   = (int*)alloc((size_t)N_NODES * 4);
    int*    rowp  = (int*)alloc((size_t)(N_NODES + 1) * 4);
    int2*   edges = (int2*)alloc((size_t)N_EDGES * 8);         // 12.8 MB packed
    unsigned int* W2g = (unsigned int*)alloc((size_t)N_CONVS * W2_LAYER * 4);  // 264 KB
    int*    blks  = (int*)alloc(128 * 4);
    int*    cursor = (int*)alloc(SUBW * 4);
    // staging (14.4 MB) aliases bufA: dead before the first agg_kernel writes bufA.
    int2*   staging = (int2*)bufA;
    (void)ws_size; (void)in_sizes; (void)n_in; (void)out_size;

    // --- bucket edges first (needs no counts), then LDS-histogram counting ---
    hipMemsetAsync(cursor, 0, SUBW * 4, stream);
    binA_kernel<<<BINA_BLOCKS, 256, 0, stream>>>(src, dst, cursor, staging);
    subcount_kernel<<<SUBW, 256, 0, stream>>>(staging, cursor, cnt);

    // --- CSR prep + W pre-pack ---
    dinv_kernel<<<(N_NODES + 255) / 256, 256, 0, stream>>>(cnt, dinv);
    scan1_kernel<<<SCAN_NBLK, 256, 0, stream>>>(cnt, rowp, blks);
    scan2_kernel<<<1, 128, 0, stream>>>(blks, SCAN_NBLK);
    scan3_kernel<<<SCAN_NBLK, 256, 0, stream>>>(rowp, blks);
    wpack_kernel<<<(N_CONVS * 16384 + 255) / 256, 256, 0, stream>>>(conv_w, W2g);

    // --- LDS-ordered coalesced CSR fill ---
    binB_kernel<<<SUBW, 512, 0, stream>>>(staging, cursor, rowp, dinv, edges);

    // --- 4 GCN layers: MFMA GEMM (fp16 out) + gather agg (fp32 out) ---
    const float* cur = x_in;
    for (int L = 0; L < N_CONVS; L++) {
        gemm_mfma_kernel<<<(N_NODES + 127) / 128, 256, 0, stream>>>(
            cur, W2g + (size_t)L * W2_LAYER, bufH);
        agg_kernel<<<(N_NODES + 3) / 4, 256, 0, stream>>>(
            (const uint4*)bufH, rowp, edges, dinv,
            (const float4*)(conv_b + (size_t)L * F), (float4*)bufA);
        cur = bufA;
    }

    // --- mean-pool + FC head ---
    pool_fc_kernel<<<N_GRAPHS, 256, 0, stream>>>(bufA, batch, fc1w, fc1b, fc2w, fc2b, out);
}

// Round 7
// 518.037 us; speedup vs baseline: 1.2950x; 1.0510x over previous
//
#include <hip/hip_runtime.h>
#include <hip/hip_fp16.h>

#define N_NODES 100000
#define N_EDGES 1600000
#define N_GRAPHS 512
#define F 128
#define N_CONVS 4
#define SCAN_NBLK ((N_NODES + 1023) / 1024)   // 98

// two-phase fill, 256 subwindows so phase-B scatter fits in LDS
#define SUBW 256
#define SUBW_NODES 391                         // ceil(100000/256)
#define SCAP 7040                              // per-subwindow staging cap (mean 6256 + 10 sigma)
#define ACHUNK 4096
#define BINA_BLOCKS ((N_EDGES + ACHUNK - 1) / ACHUNK)  // 391
#define EBUF 8192                              // LDS edge buffer (mean 6256 + 24 sigma)

// packed W2 row stride: 256 bf16 (hi/lo interleaved) padded to 264 = 132 dwords
#define W2_STRIDE 132
#define W2_LAYER (128 * W2_STRIDE)            // dwords per layer

typedef __attribute__((ext_vector_type(8))) short short8;   // 8 bf16 (4 VGPRs)
typedef __attribute__((ext_vector_type(4))) float f32x4;

union FragU { uint4 u; short8 v; };
union HU4 { uint4 u; __half2 h[4]; };

// split f into truncated-bf16 hi/lo, packed (hi in low16, lo in high16).
__device__ __forceinline__ unsigned int pack_hilo(float f) {
    unsigned int u = __float_as_uint(f);
    unsigned int hb = u & 0xFFFF0000u;
    float d = f - __uint_as_float(hb);
    unsigned int lb = __float_as_uint(d) >> 16;
    return (u >> 16) | (lb << 16);
}

// ---------------- CSR build ----------------

__global__ void dinv_kernel(const int* __restrict__ cnt, float* __restrict__ dinv) {
    int n = blockIdx.x * blockDim.x + threadIdx.x;
    if (n < N_NODES) dinv[n] = rsqrtf((float)cnt[n] + 2.0f);  // improved=True
}

__global__ void scan1_kernel(const int* __restrict__ cnt, int* __restrict__ excl,
                             int* __restrict__ blksum) {
    __shared__ int sums[256];
    int t = threadIdx.x;
    int base = blockIdx.x * 1024 + t * 4;
    int v0 = 0, v1 = 0, v2 = 0, v3 = 0;
    if (base + 0 < N_NODES) v0 = cnt[base + 0];
    if (base + 1 < N_NODES) v1 = cnt[base + 1];
    if (base + 2 < N_NODES) v2 = cnt[base + 2];
    if (base + 3 < N_NODES) v3 = cnt[base + 3];
    int s = v0 + v1 + v2 + v3;
    sums[t] = s;
    __syncthreads();
    for (int off = 1; off < 256; off <<= 1) {
        int y = (t >= off) ? sums[t - off] : 0;
        __syncthreads();
        sums[t] += y;
        __syncthreads();
    }
    int pre = sums[t] - s;
    if (base + 0 < N_NODES) excl[base + 0] = pre;
    if (base + 1 < N_NODES) excl[base + 1] = pre + v0;
    if (base + 2 < N_NODES) excl[base + 2] = pre + v0 + v1;
    if (base + 3 < N_NODES) excl[base + 3] = pre + v0 + v1 + v2;
    if (t == 255) blksum[blockIdx.x] = sums[255];
}

__global__ void scan2_kernel(int* __restrict__ blksum, int nblk) {
    __shared__ int sh[128];
    int t = threadIdx.x;
    int v = (t < nblk) ? blksum[t] : 0;
    sh[t] = v;
    __syncthreads();
    for (int off = 1; off < 128; off <<= 1) {
        int y = (t >= off) ? sh[t - off] : 0;
        __syncthreads();
        sh[t] += y;
        __syncthreads();
    }
    if (t < nblk) blksum[t] = sh[t] - v;
}

__global__ void scan3_kernel(int* __restrict__ rowptr, const int* __restrict__ blksum) {
    int t = threadIdx.x;
    int base = blockIdx.x * 1024 + t * 4;
    int off = blksum[blockIdx.x];
#pragma unroll
    for (int i = 0; i < 4; i++) {
        int idx = base + i;
        if (idx < N_NODES) rowptr[idx] += off;
    }
    if (blockIdx.x == 0 && t == 0) rowptr[N_NODES] = N_EDGES;
}

// ---------------- Two-phase CSR fill, LDS-ordered ----------------
// Measured lessons:
//  (1) gfx950 L2 does NOT merge temporally-scattered 8 B stores — every
//      global-scatter scheme paid ~6x write-back amplification. Scatter in
//      LDS, write out coalesced.
//  (2) gfx950 global atomics scattered over a small array are also ~64 B
//      write-back each (count_kernel: 50 MB WRITE for 400 KB of counters,
//      70 us). Count in LDS per subwindow instead (subcount).

__global__ __launch_bounds__(256) void binA_kernel(
        const int* __restrict__ src, const int* __restrict__ dst,
        int* __restrict__ cursor, int2* __restrict__ staging) {
    __shared__ int2 buf[ACHUNK];                 // 32 KB
    __shared__ int cnt_s[SUBW], off_s[SUBW], cur_s[SUBW], gb_s[SUBW], sh[SUBW];
    int t = threadIdx.x;
    cnt_s[t] = 0;
    __syncthreads();

    int base = blockIdx.x * ACHUNK;
    int n = N_EDGES - base;
    if (n > ACHUNK) n = ACHUNK;

    // pass 1: count bins
    for (int li = t; li < n; li += 256)
        atomicAdd(&cnt_s[dst[base + li] / SUBW_NODES], 1);
    __syncthreads();

    // exclusive scan over 256 bins
    int v = cnt_s[t];
    sh[t] = v;
    __syncthreads();
    for (int off = 1; off < SUBW; off <<= 1) {
        int y = (t >= off) ? sh[t - off] : 0;
        __syncthreads();
        sh[t] += y;
        __syncthreads();
    }
    int excl = sh[t] - v;
    off_s[t] = excl;
    cur_s[t] = excl;
    gb_s[t] = atomicAdd(&cursor[t], v);
    __syncthreads();

    // pass 2: re-read (L2-hot) and scatter into LDS bin-contiguous buffer
    for (int li = t; li < n; li += 256) {
        int e = base + li;
        int d = dst[e], s = src[e];
        int p = atomicAdd(&cur_s[d / SUBW_NODES], 1);
        buf[p] = make_int2(s, d);
    }
    __syncthreads();

    // flush: contiguous ~128 B runs per bin into per-subwindow staging
    for (int i = t; i < n; i += 256) {
        int2 e = buf[i];
        int w = e.y / SUBW_NODES;
        int idx = gb_s[w] + (i - off_s[w]);
        if (idx < SCAP) staging[(size_t)w * SCAP + idx] = e;
    }
}

__global__ __launch_bounds__(256) void subcount_kernel(
        const int2* __restrict__ staging, const int* __restrict__ cursor,
        int* __restrict__ cnt) {
    __shared__ int hist[SUBW_NODES];
    int b = blockIdx.x, t = threadIdx.x;
    int n0 = b * SUBW_NODES;
    int n1 = n0 + SUBW_NODES;
    if (n1 > N_NODES) n1 = N_NODES;
    int nn = n1 - n0;
    for (int i = t; i < nn; i += 256) hist[i] = 0;
    __syncthreads();
    int m = cursor[b];
    if (m > SCAP) m = SCAP;
    for (int i = t; i < m; i += 256) {
        int d = staging[(size_t)b * SCAP + i].y;
        atomicAdd(&hist[d - n0], 1);
    }
    __syncthreads();
    for (int i = t; i < nn; i += 256) cnt[n0 + i] = hist[i];
}

__global__ __launch_bounds__(512) void binB_kernel(
        const int2* __restrict__ staging, const int* __restrict__ cursor,
        const int* __restrict__ rowptr, const float* __restrict__ dinv,
        int2* __restrict__ edges) {
    __shared__ int rowl[SUBW_NODES + 1];
    __shared__ int lcur[SUBW_NODES];
    __shared__ int2 ebuf[EBUF];                  // 64 KB
    int b = blockIdx.x, t = threadIdx.x;
    int n0 = b * SUBW_NODES;
    int n1 = n0 + SUBW_NODES;
    if (n1 > N_NODES) n1 = N_NODES;
    int nn = n1 - n0;

    for (int i = t; i <= nn; i += 512) rowl[i] = rowptr[n0 + i];
    for (int i = t; i < nn; i += 512) lcur[i] = 0;
    __syncthreads();

    int gb = rowl[0];
    int total = rowl[nn] - gb;
    int m = cursor[b];
    if (m > SCAP) m = SCAP;

    for (int i = t; i < m; i += 512) {
        int2 e = staging[(size_t)b * SCAP + i];
        int s = e.x, d = e.y;
        float wt = dinv[s] * dinv[d];
        int dl = d - n0;
        int lpos = (rowl[dl] - gb) + atomicAdd(&lcur[dl], 1);
        if (lpos < EBUF) ebuf[lpos] = make_int2(s, __float_as_int(wt));
    }
    __syncthreads();

    // fully coalesced ordered write-out of this subwindow's CSR range
    for (int i = t; i < total; i += 512)
        if (i < EBUF) edges[gb + i] = ebuf[i];
}

// ---------------- W pre-pack: conv_w[L][k][n] -> W2g[L][n][132 dwords] ----------------

__global__ void wpack_kernel(const float* __restrict__ conv_w, unsigned int* __restrict__ W2g) {
    int idx = blockIdx.x * 256 + threadIdx.x;
    if (idx < N_CONVS * 16384) {
        int L = idx >> 14;
        int e = idx & 16383;
        int k = e >> 7;
        int n = e & 127;
        float f = conv_w[(size_t)L * 16384 + k * 128 + n];
        W2g[(size_t)L * W2_LAYER + n * W2_STRIDE + k] = pack_hilo(f);
    }
}

// ---------------- MFMA GEMM: H = X @ W via split-bf16, 32 rows/wave, fp16 out ------
// Templated on input dtype: layer 0 reads fp32 x_in; layers 1-3 read fp16 bufA
// (fp16 node features halve agg-write + gemm-read + pool-read traffic).

template<bool F16IN>
__global__ __launch_bounds__(256, 2) void gemm_mfma_t(const void* __restrict__ Xv,
                                                      const unsigned int* __restrict__ W2g,
                                                      __half* __restrict__ Hh) {
    __shared__ unsigned int wlds[128 * W2_STRIDE];   // 67584 B
    int t = threadIdx.x;

    {   // stage packed W (16896 dwords)
        const uint4* s4 = (const uint4*)W2g;
        uint4* d4 = (uint4*)wlds;
#pragma unroll
        for (int i = 0; i < 17; i++) {
            int idx = i * 256 + t;
            if (idx < (128 * W2_STRIDE) / 4) d4[idx] = s4[idx];
        }
    }
    __syncthreads();

    int w = t >> 6;
    int l = t & 63;
    int m = l & 15;        // A row within tile / B col / C col
    int q = l >> 4;        // quad: k-offset q*8, C row-offset q*4
    int r0 = blockIdx.x * 128 + w * 32 + m;
    int r1 = r0 + 16;
    int r0c = (r0 > N_NODES - 1) ? (N_NODES - 1) : r0;
    int r1c = (r1 > N_NODES - 1) ? (N_NODES - 1) : r1;

    uint4 a0[8], a1[8];
#pragma unroll
    for (int i = 0; i < 8; i++) {
        if constexpr (F16IN) {
            const uint2* X2 = (const uint2*)Xv;   // 32 uint2 (4 halves each) per row
            uint2 hv = X2[(size_t)r0c * 32 + i * 4 + q];
            float2 f0 = __half22float2(*(const __half2*)&hv.x);
            float2 f1 = __half22float2(*(const __half2*)&hv.y);
            a0[i].x = pack_hilo(f0.x); a0[i].y = pack_hilo(f0.y);
            a0[i].z = pack_hilo(f1.x); a0[i].w = pack_hilo(f1.y);
            uint2 gv = X2[(size_t)r1c * 32 + i * 4 + q];
            float2 g0 = __half22float2(*(const __half2*)&gv.x);
            float2 g1 = __half22float2(*(const __half2*)&gv.y);
            a1[i].x = pack_hilo(g0.x); a1[i].y = pack_hilo(g0.y);
            a1[i].z = pack_hilo(g1.x); a1[i].w = pack_hilo(g1.y);
        } else {
            const float4* X4 = (const float4*)Xv;
            float4 xv = X4[(size_t)r0c * 32 + i * 4 + q];
            a0[i].x = pack_hilo(xv.x); a0[i].y = pack_hilo(xv.y);
            a0[i].z = pack_hilo(xv.z); a0[i].w = pack_hilo(xv.w);
            float4 yv = X4[(size_t)r1c * 32 + i * 4 + q];
            a1[i].x = pack_hilo(yv.x); a1[i].y = pack_hilo(yv.y);
            a1[i].z = pack_hilo(yv.z); a1[i].w = pack_hilo(yv.w);
        }
    }

    f32x4 acc0[8], acc1[8];
#pragma unroll
    for (int nb = 0; nb < 8; nb++) {
        acc0[nb] = (f32x4){0.f, 0.f, 0.f, 0.f};
        acc1[nb] = (f32x4){0.f, 0.f, 0.f, 0.f};
    }

#pragma unroll
    for (int nb = 0; nb < 8; nb++) {
        const unsigned int* wb = &wlds[(nb * 16 + m) * W2_STRIDE];
#pragma unroll
        for (int i = 0; i < 8; i++) {
            uint4 b = *(const uint4*)(wb + i * 16 + q * 4);
            FragU fa0, fa1, fb, fr;
            fa0.u = a0[i]; fa1.u = a1[i]; fb.u = b;
            acc0[nb] = __builtin_amdgcn_mfma_f32_16x16x32_bf16(fa0.v, fb.v, acc0[nb], 0, 0, 0);
            acc1[nb] = __builtin_amdgcn_mfma_f32_16x16x32_bf16(fa1.v, fb.v, acc1[nb], 0, 0, 0);
            fr.u.x = (b.x >> 16) | (b.x << 16);
            fr.u.y = (b.y >> 16) | (b.y << 16);
            fr.u.z = (b.z >> 16) | (b.z << 16);
            fr.u.w = (b.w >> 16) | (b.w << 16);
            acc0[nb] = __builtin_amdgcn_mfma_f32_16x16x32_bf16(fa0.v, fr.v, acc0[nb], 0, 0, 0);
            acc1[nb] = __builtin_amdgcn_mfma_f32_16x16x32_bf16(fa1.v, fr.v, acc1[nb], 0, 0, 0);
        }
    }

    // C/D: col = m, row = q*4 + r within tile
    int rbase = blockIdx.x * 128 + w * 32 + q * 4;
#pragma unroll
    for (int nb = 0; nb < 8; nb++) {
#pragma unroll
        for (int r = 0; r < 4; r++) {
            int row = rbase + r;
            if (row < N_NODES) Hh[(size_t)row * F + nb * 16 + m] = __float2half(acc0[nb][r]);
            int row1 = row + 16;
            if (row1 < N_NODES) Hh[(size_t)row1 * F + nb * 16 + m] = __float2half(acc1[nb][r]);
        }
    }
}

// ---------------- Aggregation: x_out = relu(agg + 2*dinv^2*h + b), fp16 in/out ----
// One wave per node; lane = (slot = lane>>4, c16 = lane&15); uint4 gathers
// (8 fp16 channels/lane, 16 lane-requests per H-row, 4 edges per instruction).
// FETCH ~195 MB is the structural floor (8 XCDs x 25.6 MB H, private L2s);
// output now fp16 (uint4 of 8 halves per lane) halving WRITE 50 -> 25 MB.

__global__ __launch_bounds__(256) void agg_kernel(const uint4* __restrict__ H16,
                                                  const int* __restrict__ rowptr,
                                                  const int2* __restrict__ edges,
                                                  const float* __restrict__ dinv,
                                                  const float4* __restrict__ bias4,
                                                  uint4* __restrict__ Xo) {
    int node = blockIdx.x * 4 + (threadIdx.x >> 6);
    if (node >= N_NODES) return;
    int lane = threadIdx.x & 63;
    int c16 = lane & 15;
    int slot = lane >> 4;

    int lo = rowptr[node];
    int hi = rowptr[node + 1];
    int him1 = hi - 1;

    float4 aL = make_float4(0.f, 0.f, 0.f, 0.f);
    float4 aH = make_float4(0.f, 0.f, 0.f, 0.f);

    for (int i = lo + slot; i < hi; i += 16) {
        int s[4]; float w[4]; uint4 v[4];
#pragma unroll
        for (int j = 0; j < 4; j++) {
            int ij = i + 4 * j;
            int cj = (ij < him1) ? ij : him1;
            int2 e = edges[cj];
            s[j] = e.x;
            w[j] = (ij < hi) ? __int_as_float(e.y) : 0.f;
        }
#pragma unroll
        for (int j = 0; j < 4; j++) v[j] = H16[(size_t)s[j] * 16 + c16];
#pragma unroll
        for (int j = 0; j < 4; j++) {
            HU4 x; x.u = v[j];
            float2 p0 = __half22float2(x.h[0]);
            float2 p1 = __half22float2(x.h[1]);
            float2 p2 = __half22float2(x.h[2]);
            float2 p3 = __half22float2(x.h[3]);
            aL.x = fmaf(w[j], p0.x, aL.x); aL.y = fmaf(w[j], p0.y, aL.y);
            aL.z = fmaf(w[j], p1.x, aL.z); aL.w = fmaf(w[j], p1.y, aL.w);
            aH.x = fmaf(w[j], p2.x, aH.x); aH.y = fmaf(w[j], p2.y, aH.y);
            aH.z = fmaf(w[j], p3.x, aH.z); aH.w = fmaf(w[j], p3.y, aH.w);
        }
    }

    aL.x += __shfl_down(aL.x, 32, 64); aL.y += __shfl_down(aL.y, 32, 64);
    aL.z += __shfl_down(aL.z, 32, 64); aL.w += __shfl_down(aL.w, 32, 64);
    aH.x += __shfl_down(aH.x, 32, 64); aH.y += __shfl_down(aH.y, 32, 64);
    aH.z += __shfl_down(aH.z, 32, 64); aH.w += __shfl_down(aH.w, 32, 64);
    aL.x += __shfl_down(aL.x, 16, 64); aL.y += __shfl_down(aL.y, 16, 64);
    aL.z += __shfl_down(aL.z, 16, 64); aL.w += __shfl_down(aL.w, 16, 64);
    aH.x += __shfl_down(aH.x, 16, 64); aH.y += __shfl_down(aH.y, 16, 64);
    aH.z += __shfl_down(aH.z, 16, 64); aH.w += __shfl_down(aH.w, 16, 64);

    if (slot == 0) {
        float dn = dinv[node];
        float sw = 2.0f * dn * dn;
        HU4 x; x.u = H16[(size_t)node * 16 + c16];
        float2 p0 = __half22float2(x.h[0]);
        float2 p1 = __half22float2(x.h[1]);
        float2 p2 = __half22float2(x.h[2]);
        float2 p3 = __half22float2(x.h[3]);
        float4 bL = bias4[c16 * 2];
        float4 bH = bias4[c16 * 2 + 1];
        float4 rL, rH;
        rL.x = fmaxf(fmaf(sw, p0.x, aL.x) + bL.x, 0.f);
        rL.y = fmaxf(fmaf(sw, p0.y, aL.y) + bL.y, 0.f);
        rL.z = fmaxf(fmaf(sw, p1.x, aL.z) + bL.z, 0.f);
        rL.w = fmaxf(fmaf(sw, p1.y, aL.w) + bL.w, 0.f);
        rH.x = fmaxf(fmaf(sw, p2.x, aH.x) + bH.x, 0.f);
        rH.y = fmaxf(fmaf(sw, p2.y, aH.y) + bH.y, 0.f);
        rH.z = fmaxf(fmaf(sw, p3.x, aH.z) + bH.z, 0.f);
        rH.w = fmaxf(fmaf(sw, p3.y, aH.w) + bH.w, 0.f);
        HU4 o;
        o.h[0] = __floats2half2_rn(rL.x, rL.y);
        o.h[1] = __floats2half2_rn(rL.z, rL.w);
        o.h[2] = __floats2half2_rn(rH.x, rH.y);
        o.h[3] = __floats2half2_rn(rH.z, rH.w);
        Xo[(size_t)node * 16 + c16] = o.u;
    }
}

// ---------------- Fused mean-pool + FC1(relu) + FC2 (fp16 x) ----------------

__global__ __launch_bounds__(256) void pool_fc_kernel(const __half* __restrict__ x,
                                                      const int* __restrict__ batch,
                                                      const float* __restrict__ fc1w,
                                                      const float* __restrict__ fc1b,
                                                      const float* __restrict__ fc2w,
                                                      const float* __restrict__ fc2b,
                                                      float* __restrict__ out) {
    __shared__ float part[2][F];
    __shared__ float pooled[F];
    __shared__ int bnd[2];
    __shared__ float red[2];
    int g = blockIdx.x, t = threadIdx.x;
    int c = t & 127, hlf = t >> 7;

    if (t < 2) {
        int target = g + t;
        int lo = 0, hi = N_NODES;
        while (lo < hi) {
            int m = (lo + hi) >> 1;
            if (batch[m] < target) lo = m + 1;
            else hi = m;
        }
        bnd[t] = lo;
    }
    __syncthreads();
    int lo = bnd[0], hi = bnd[1];

    float s = 0.f;
    int n = lo + hlf;
    for (; n + 6 < hi; n += 8) {
        float v0 = __half2float(x[(size_t)n * F + c]);
        float v1 = __half2float(x[(size_t)(n + 2) * F + c]);
        float v2 = __half2float(x[(size_t)(n + 4) * F + c]);
        float v3 = __half2float(x[(size_t)(n + 6) * F + c]);
        s += (v0 + v1) + (v2 + v3);
    }
    for (; n < hi; n += 2) s += __half2float(x[(size_t)n * F + c]);
    part[hlf][c] = s;
    __syncthreads();

    if (t < F) {
        float cntf = fmaxf((float)(hi - lo), 1.0f);
        pooled[c] = (part[0][c] + part[1][c]) / cntf;
    }
    __syncthreads();

    if (t < F) {
        float acc = fc1b[t];
#pragma unroll 4
        for (int k = 0; k < F; k++) acc = fmaf(pooled[k], fc1w[k * F + t], acc);
        acc = fmaxf(acc, 0.f);

        float p = acc * fc2w[t];
#pragma unroll
        for (int o = 32; o > 0; o >>= 1) p += __shfl_down(p, o, 64);
        if ((t & 63) == 0) red[t >> 6] = p;
    }
    __syncthreads();
    if (t == 0) out[g] = red[0] + red[1] + fc2b[0];
}

// ---------------- launch ----------------

extern "C" void kernel_launch(void* const* d_in, const int* in_sizes, int n_in,
                              void* d_out, int out_size, void* d_ws, size_t ws_size,
                              hipStream_t stream) {
    const float* x_in   = (const float*)d_in[0];
    const int*   eidx   = (const int*)d_in[1];
    const int*   batch  = (const int*)d_in[2];
    const float* conv_w = (const float*)d_in[4];
    const float* conv_b = (const float*)d_in[5];
    const float* fc1w   = (const float*)d_in[6];
    const float* fc1b   = (const float*)d_in[7];
    const float* fc2w   = (const float*)d_in[8];
    const float* fc2b   = (const float*)d_in[9];
    float* out = (float*)d_out;

    const int* src = eidx;
    const int* dst = eidx + N_EDGES;

    char* ws = (char*)d_ws;
    size_t off = 0;
    auto alloc = [&](size_t bytes) -> char* {
        char* p = ws + off;
        off += (bytes + 255) & ~(size_t)255;
        return p;
    };
    __half* bufA  = (__half*)alloc((size_t)N_NODES * F * 2);   // 25.6 MB fp16 (agg out)
    __half* bufH  = (__half*)alloc((size_t)N_NODES * F * 2);   // 25.6 MB fp16 (gemm out)
    float*  dinv  = (float*)alloc((size_t)N_NODES * 4);
    int*    cnt   = (int*)alloc((size_t)N_NODES * 4);
    int*    rowp  = (int*)alloc((size_t)(N_NODES + 1) * 4);
    int2*   edges = (int2*)alloc((size_t)N_EDGES * 8);         // 12.8 MB packed
    unsigned int* W2g = (unsigned int*)alloc((size_t)N_CONVS * W2_LAYER * 4);  // 264 KB
    int*    blks  = (int*)alloc(128 * 4);
    int*    cursor = (int*)alloc(SUBW * 4);
    // staging (14.4 MB) gets its own region: bufA is only 25.6 MB now and
    // staging must survive until binB, which runs after other prep.
    int2*   staging = (int2*)alloc((size_t)SUBW * SCAP * 8);   // 14.4 MB
    (void)ws_size; (void)in_sizes; (void)n_in; (void)out_size;

    // --- bucket edges first (needs no counts), then LDS-histogram counting ---
    hipMemsetAsync(cursor, 0, SUBW * 4, stream);
    binA_kernel<<<BINA_BLOCKS, 256, 0, stream>>>(src, dst, cursor, staging);
    subcount_kernel<<<SUBW, 256, 0, stream>>>(staging, cursor, cnt);

    // --- CSR prep + W pre-pack ---
    dinv_kernel<<<(N_NODES + 255) / 256, 256, 0, stream>>>(cnt, dinv);
    scan1_kernel<<<SCAN_NBLK, 256, 0, stream>>>(cnt, rowp, blks);
    scan2_kernel<<<1, 128, 0, stream>>>(blks, SCAN_NBLK);
    scan3_kernel<<<SCAN_NBLK, 256, 0, stream>>>(rowp, blks);
    wpack_kernel<<<(N_CONVS * 16384 + 255) / 256, 256, 0, stream>>>(conv_w, W2g);

    // --- LDS-ordered coalesced CSR fill ---
    binB_kernel<<<SUBW, 512, 0, stream>>>(staging, cursor, rowp, dinv, edges);

    // --- 4 GCN layers: MFMA GEMM (fp16 out) + gather agg (fp16 out) ---
    for (int L = 0; L < N_CONVS; L++) {
        if (L == 0)
            gemm_mfma_t<false><<<(N_NODES + 127) / 128, 256, 0, stream>>>(
                (const void*)x_in, W2g, bufH);
        else
            gemm_mfma_t<true><<<(N_NODES + 127) / 128, 256, 0, stream>>>(
                (const void*)bufA, W2g + (size_t)L * W2_LAYER, bufH);
        agg_kernel<<<(N_NODES + 3) / 4, 256, 0, stream>>>(
            (const uint4*)bufH, rowp, edges, dinv,
            (const float4*)(conv_b + (size_t)L * F), (uint4*)bufA);
    }

    // --- mean-pool + FC head ---
    pool_fc_kernel<<<N_GRAPHS, 256, 0, stream>>>(bufA, batch, fc1w, fc1b, fc2w, fc2b, out);
}